// Round 16
// baseline (661.389 us; speedup 1.0000x reference)
//
#include <hip/hip_runtime.h>

namespace {
constexpr int V = 50000;
constexpr int E = 640000;
constexpr int HALF = 320000;
constexpr int NREL2 = 474;
constexpr int C = 128;
constexpr int NCHUNK = (V + 255) / 256; // 196
constexpr int NQBLK = V / 16;           // 3125 node-blocks in qnode
constexpr int RELBLK = (NREL2 + 1) / 2; // 237 relout blocks folded into qnode
constexpr int HISTBLK = E / 256;        // 2500 hist blocks folded into qnode
constexpr int NTILES = V / 16;          // 3125
}

typedef _Float16 h4 __attribute__((ext_vector_type(4)));
typedef _Float16 f16x8 __attribute__((ext_vector_type(8)));
typedef float f32x4 __attribute__((ext_vector_type(4)));

// ---- precompute: c[k,i], b[k,i], Mh + LWh (f16 frag layouts), rel_h cast ---
__global__ void prep_kernel(const float* __restrict__ nrw, const float* __restrict__ nw,
                            const float* __restrict__ inw, const float* __restrict__ outw,
                            const float* __restrict__ aw, const float* __restrict__ rel,
                            const float* __restrict__ lr, const float* __restrict__ lw,
                            float* __restrict__ cbuf, float* __restrict__ bbuf,
                            _Float16* __restrict__ Mh, _Float16* __restrict__ rel_h,
                            _Float16* __restrict__ LWh) {
  int tid = blockIdx.x * 256 + threadIdx.x;
  if (tid < 512) {
    int k = tid >> 7, i = tid & 127;
    float acc = 0.f;
    for (int d = 0; d < 32; ++d) acc += nrw[k*4096 + i*32 + d] * aw[d];
    cbuf[tid] = acc;
  } else if (tid < 1024) {
    int u = tid - 512; int k = u >> 7, i = u & 127;
    float acc = 0.f;
    for (int d = 0; d < 32; ++d) acc += nw[k*4096 + i*32 + d] * aw[32 + d];
    bbuf[u] = acc;
  } else if (tid < 1024 + 16384) {
    int u = tid - 1024; int k = u >> 12, rem = u & 4095, i = rem >> 5, o = rem & 31;
    float acc = 0.f;
    for (int d = 0; d < 32; ++d) acc += nrw[k*4096 + i*32 + d] * inw[k*1024 + d*32 + o];
    Mh[(((k) * 2 + (o >> 4)) * 16 + (o & 15)) * 128 + i] = (_Float16)acc;
  } else if (tid < 1024 + 32768) {
    int u = tid - 1024 - 16384; int k = u >> 12, rem = u & 4095, i = rem >> 5, o = rem & 31;
    float acc = 0.f;
    for (int d = 0; d < 32; ++d) acc += nrw[k*4096 + i*32 + d] * outw[k*1024 + d*32 + o];
    Mh[(((4 + k) * 2 + (o >> 4)) * 16 + (o & 15)) * 128 + i] = (_Float16)acc;
  } else if (tid < 1024 + 32768 + NREL2 * C / 8) {
    int u = tid - 1024 - 32768;  // 8-elem chunk of rel table
    const float4 v0 = *(const float4*)(rel + (size_t)u * 8);
    const float4 v1 = *(const float4*)(rel + (size_t)u * 8 + 4);
    f16x8 o;
    o[0] = (_Float16)v0.x; o[1] = (_Float16)v0.y;
    o[2] = (_Float16)v0.z; o[3] = (_Float16)v0.w;
    o[4] = (_Float16)v1.x; o[5] = (_Float16)v1.y;
    o[6] = (_Float16)v1.z; o[7] = (_Float16)v1.w;
    *(f16x8*)(rel_h + (size_t)u * 8) = o;
  } else if (tid < 1024 + 32768 + NREL2 * C / 8 + 16384) {
    int u = tid - 1024 - 32768 - NREL2 * C / 8;  // [o(128)][i(128)]
    int o = u >> 7, i = u & 127;
    float v = lr[i] * lw[i * C + o] * (1.f / 3.f);
    LWh[u] = (_Float16)v;
  }
}

// ---- q[t,k] = node_repr[t].b_k (16 lanes/node) + f16 node cast.
// Blocks [NQBLK, NQBLK+RELBLK): rel_out. Blocks beyond: edge histogram. -----
__global__ __launch_bounds__(256) void qnode_kernel(const float* __restrict__ nrp,
                                                    const float* __restrict__ bbuf,
                                                    float* __restrict__ qbuf,
                                                    _Float16* __restrict__ nrp_h,
                                                    const float* __restrict__ rel,
                                                    const float* __restrict__ wrel,
                                                    float* __restrict__ rel_out,
                                                    const int* __restrict__ dst,
                                                    int* __restrict__ cnt,
                                                    int* __restrict__ cin) {
  if (blockIdx.x >= NQBLK + RELBLK) {  // folded histogram
    int e = (blockIdx.x - NQBLK - RELBLK) * 256 + threadIdx.x;
    if (e < E) {
      int t = dst[e];
      atomicAdd(&cnt[t], 1);
      if (e < HALF) atomicAdd(&cin[t], 1);
    }
    return;
  }
  if (blockIdx.x >= NQBLK) {  // folded relout (block-uniform branch)
    __shared__ float rr2[2][128];
    const int bb = blockIdx.x - NQBLK;
    const int half = threadIdx.x >> 7;
    const int t128 = threadIdx.x & 127;
    const int row = bb * 2 + half;
    if (row < NREL2) rr2[half][t128] = rel[row * C + t128];
    __syncthreads();
    if (row < NREL2) {
      float acc = 0.f;
#pragma unroll 4
      for (int i = 0; i < C; ++i) acc += rr2[half][i] * wrel[i * C + t128];
      rel_out[row * C + t128] = acc;
    }
    return;
  }
  const int t = blockIdx.x * 16 + (threadIdx.x >> 4);
  const int l = threadIdx.x & 15;
  if (t >= V) return;
  const float* row = nrp + (size_t)t * C + l * 8;
  float4 a0 = *(const float4*)(row);
  float4 a1 = *(const float4*)(row + 4);
  {
    f16x8 o;
    o[0] = (_Float16)a0.x; o[1] = (_Float16)a0.y;
    o[2] = (_Float16)a0.z; o[3] = (_Float16)a0.w;
    o[4] = (_Float16)a1.x; o[5] = (_Float16)a1.y;
    o[6] = (_Float16)a1.z; o[7] = (_Float16)a1.w;
    *(f16x8*)(nrp_h + (size_t)t * C + l * 8) = o;
  }
  float p[4];
#pragma unroll
  for (int k = 0; k < 4; ++k) {
    const float* brow = bbuf + k * C + l * 8;
    float4 b0 = *(const float4*)(brow);
    float4 b1 = *(const float4*)(brow + 4);
    p[k] = a0.x * b0.x + a0.y * b0.y + a0.z * b0.z + a0.w * b0.w
         + a1.x * b1.x + a1.y * b1.y + a1.z * b1.z + a1.w * b1.w;
  }
#pragma unroll
  for (int m = 1; m < 16; m <<= 1) {
#pragma unroll
    for (int k = 0; k < 4; ++k) p[k] += __shfl_xor(p[k], m);
  }
  if (l == 0) *(float4*)(qbuf + 4 * (size_t)t) = make_float4(p[0], p[1], p[2], p[3]);
}

// ---------------- CSR scan ---------------------------------------------------
__global__ void scan_sum_kernel(const int* __restrict__ cnt, int* __restrict__ bsum) {
  __shared__ int sd[256];
  int tid = threadIdx.x;
  int idx = blockIdx.x * 256 + tid;
  int v = (idx < V) ? cnt[idx] : 0;
  sd[tid] = v; __syncthreads();
  for (int s = 128; s > 0; s >>= 1) {
    if (tid < s) sd[tid] += sd[tid + s];
    __syncthreads();
  }
  if (tid == 0) bsum[blockIdx.x] = sd[0];
}

// per-block scan + redundant top-scan (folds scan_top); ninfo = {off,deg,nin};
// also histogram nodes by nmax (for degree-balanced fused mapping)
__global__ void scan_apply_kernel(const int* __restrict__ cnt, const int* __restrict__ cin,
                                  const int* __restrict__ bsum, int4* __restrict__ ninfo,
                                  int* __restrict__ khist) {
  __shared__ int sd[256];
  __shared__ int sb[256];
  int tid = threadIdx.x;
  int idx = blockIdx.x * 256 + tid;
  // top-scan (inclusive) of block sums — redundant per block, cheap
  int b = (tid < NCHUNK) ? bsum[tid] : 0;
  sb[tid] = b; __syncthreads();
  for (int ofs = 1; ofs < 256; ofs <<= 1) {
    int t2 = (tid >= ofs) ? sb[tid - ofs] : 0;
    __syncthreads();
    sb[tid] += t2;
    __syncthreads();
  }
  const int blockoff = (blockIdx.x == 0) ? 0 : sb[blockIdx.x - 1];
  // per-node scan
  int v = (idx < V) ? cnt[idx] : 0;
  sd[tid] = v; __syncthreads();
  for (int ofs = 1; ofs < 256; ofs <<= 1) {
    int t2 = (tid >= ofs) ? sd[tid - ofs] : 0;
    __syncthreads();
    sd[tid] += t2;
    __syncthreads();
  }
  if (idx < V) {
    int ci = cin[idx];
    ninfo[idx] = make_int4(blockoff + sd[tid] - v, v, ci, 0);
    int key = min(max(ci, v - ci), 255);
    atomicAdd(&khist[key], 1);
  }
}

// exclusive scan of the 256-bin degree histogram (1 block)
__global__ void keyscan_kernel(int* __restrict__ khist) {
  __shared__ int sd[256];
  int tid = threadIdx.x;
  int v = khist[tid];
  sd[tid] = v; __syncthreads();
  for (int ofs = 1; ofs < 256; ofs <<= 1) {
    int t2 = (tid >= ofs) ? sd[tid - ofs] : 0;
    __syncthreads();
    sd[tid] += t2;
    __syncthreads();
  }
  khist[tid] = sd[tid] - v;  // exclusive
}

// place edges (in-edges first within node) + place nodes into degree-sorted
// order (snodes). Blocks >= E/256 do the node placement.
__global__ void place_kernel(const int* __restrict__ dst, const int* __restrict__ src,
                             const int* __restrict__ etype, const float* __restrict__ norm,
                             const int4* __restrict__ ninfo,
                             int* __restrict__ cur_in, int* __restrict__ cur_out,
                             int2* __restrict__ em,
                             const int* __restrict__ khist, int* __restrict__ kcur,
                             int* __restrict__ snodes) {
  if (blockIdx.x >= E / 256) {  // node placement (degree-sorted)
    int t = (blockIdx.x - E / 256) * 256 + threadIdx.x;
    if (t < V) {
      int4 nf = ninfo[t];
      int key = min(max(nf.z, nf.y - nf.z), 255);
      int pos = khist[key] + atomicAdd(&kcur[key], 1);
      snodes[pos] = t;
    }
    return;
  }
  int e = blockIdx.x * 256 + threadIdx.x;
  {
    int t = dst[e];
    int4 nf = ninfo[t];
    int pos;
    if (e < HALF) {
      pos = nf.x + atomicAdd(&cur_in[t], 1);
    } else {
      pos = nf.x + nf.z + atomicAdd(&cur_out[t], 1);
    }
    em[pos] = make_int2(src[e] | (etype[e] << 16), __float_as_int(norm[e]));
  }
}

// ---------------- fused: gather + attention + z accum + MFMA ----------------
// Round-9 config + degree-balanced node mapping: block b, wave w, slot nn
// processes sorted-rank nn*4*NTILES + w*NTILES + b — every wave and every
// block spans the degree distribution uniformly (no barrier/drain waste).
__global__ __launch_bounds__(256) void fused_kernel(
    const _Float16* __restrict__ nrp_h, const _Float16* __restrict__ rel_h,
    const int4* __restrict__ ninfo, const float* __restrict__ qbuf,
    const float* __restrict__ cbuf, const int2* __restrict__ em,
    const _Float16* __restrict__ Mh, const int* __restrict__ snodes,
    float* __restrict__ h) {
  __shared__ __align__(16) _Float16 z16[16384];  // 16 nodes x 2048B, swizzled
  const int w = threadIdx.x >> 6;
  const int lane = threadIdx.x & 63;
  const int dirg = lane >> 5;        // 0: in-edges, 1: out-edges
  const int slot = (lane >> 4) & 1;  // edge slot within dir
  const int ll = lane & 15;          // 8-channel chunk
  const int ch0 = ll * 8;

  // c_k chunks: register-resident (8 floats per k)
  float4 ckA[4], ckB[4];
#pragma unroll
  for (int k = 0; k < 4; ++k) {
    ckA[k] = *(const float4*)(cbuf + k * C + ch0);
    ckB[k] = *(const float4*)(cbuf + k * C + ch0 + 4);
  }

  // ---- phase 1: per-node edge loop, 4 edges per wave-iteration ----
  for (int nn = 0; nn < 4; ++nn) {
    const int node = w * 4 + nn;               // block-local 0..15
    const int t = snodes[nn * 4 * NTILES + w * NTILES + blockIdx.x];
    const int4 nfo = ninfo[t];
    const int start = nfo.x, deg = nfo.y, ni = nfo.z;
    const float4 q4 = *(const float4*)(qbuf + 4 * (size_t)t);
    const int sidx = dirg ? ni : 0;
    const int nmy = dirg ? (deg - ni) : ni;
    const int nmax = max(ni, deg - ni);        // wave-uniform

    float4 zA[4], zB[4];
#pragma unroll
    for (int k = 0; k < 4; ++k) {
      zA[k] = make_float4(0.f, 0.f, 0.f, 0.f);
      zB[k] = make_float4(0.f, 0.f, 0.f, 0.f);
    }

    if (nmax > 0) {
      // stage: em0 -> current (j), em1 -> next (j+2); rows for j in flight
      int2 em0 = em[start + min(sidx + slot, deg - 1)];
      int2 em1 = em[start + min(sidx + 2 + slot, deg - 1)];
      f16x8 ah = *(const f16x8*)(nrp_h + (size_t)(em0.x & 0xFFFF) * C + ch0);
      f16x8 bh = *(const f16x8*)(rel_h + (size_t)((em0.x >> 16) & 0x1FF) * C + ch0);

      for (int j = 0; j < nmax; j += 2) {
        // stage meta for j+4 (no dependencies; wave-uniform condition)
        int2 em2 = em1;
        if (j + 4 < nmax) em2 = em[start + min(sidx + j + 4 + slot, deg - 1)];
        // stage rows for j+2 using em1 (arrived a full iteration ago)
        f16x8 ahn = ah, bhn = bh;
        if (j + 2 < nmax) {
          ahn = *(const f16x8*)(nrp_h + (size_t)(em1.x & 0xFFFF) * C + ch0);
          bhn = *(const f16x8*)(rel_h + (size_t)((em1.x >> 16) & 0x1FF) * C + ch0);
        }
        // compute current edge (j + slot): x = a*b in f32
        float4 xA, xB;
        xA.x = (float)ah[0] * (float)bh[0];
        xA.y = (float)ah[1] * (float)bh[1];
        xA.z = (float)ah[2] * (float)bh[2];
        xA.w = (float)ah[3] * (float)bh[3];
        xB.x = (float)ah[4] * (float)bh[4];
        xB.y = (float)ah[5] * (float)bh[5];
        xB.z = (float)ah[6] * (float)bh[6];
        xB.w = (float)ah[7] * (float)bh[7];
        float p0 = xA.x * ckA[0].x + xA.y * ckA[0].y + xA.z * ckA[0].z + xA.w * ckA[0].w
                 + xB.x * ckB[0].x + xB.y * ckB[0].y + xB.z * ckB[0].z + xB.w * ckB[0].w;
        float p1 = xA.x * ckA[1].x + xA.y * ckA[1].y + xA.z * ckA[1].z + xA.w * ckA[1].w
                 + xB.x * ckB[1].x + xB.y * ckB[1].y + xB.z * ckB[1].z + xB.w * ckB[1].w;
        float p2 = xA.x * ckA[2].x + xA.y * ckA[2].y + xA.z * ckA[2].z + xA.w * ckA[2].w
                 + xB.x * ckB[2].x + xB.y * ckB[2].y + xB.z * ckB[2].z + xB.w * ckB[2].w;
        float p3 = xA.x * ckA[3].x + xA.y * ckA[3].y + xA.z * ckA[3].z + xA.w * ckA[3].w
                 + xB.x * ckB[3].x + xB.y * ckB[3].y + xB.z * ckB[3].z + xB.w * ckB[3].w;
#pragma unroll
        for (int m = 1; m < 16; m <<= 1) {
          p0 += __shfl_xor(p0, m);
          p1 += __shfl_xor(p1, m);
          p2 += __shfl_xor(p2, m);
          p3 += __shfl_xor(p3, m);
        }
        // softmax (no max-sub: logits are relu'd and small for this model)
        float l0 = fmaxf(p0 + q4.x, 0.f);
        float l1 = fmaxf(p1 + q4.y, 0.f);
        float l2 = fmaxf(p2 + q4.z, 0.f);
        float l3 = fmaxf(p3 + q4.w, 0.f);
        float e0f = __expf(l0), e1f = __expf(l1);
        float e2f = __expf(l2), e3f = __expf(l3);
        float nr = __int_as_float(em0.y);
        float inv = ((j + slot) < nmy) ? (nr / (e0f + e1f + e2f + e3f)) : 0.f;
        float w0 = e0f * inv, w1 = e1f * inv, w2 = e2f * inv, w3 = e3f * inv;
        zA[0].x += w0 * xA.x; zA[0].y += w0 * xA.y; zA[0].z += w0 * xA.z; zA[0].w += w0 * xA.w;
        zB[0].x += w0 * xB.x; zB[0].y += w0 * xB.y; zB[0].z += w0 * xB.z; zB[0].w += w0 * xB.w;
        zA[1].x += w1 * xA.x; zA[1].y += w1 * xA.y; zA[1].z += w1 * xA.z; zA[1].w += w1 * xA.w;
        zB[1].x += w1 * xB.x; zB[1].y += w1 * xB.y; zB[1].z += w1 * xB.z; zB[1].w += w1 * xB.w;
        zA[2].x += w2 * xA.x; zA[2].y += w2 * xA.y; zA[2].z += w2 * xA.z; zA[2].w += w2 * xA.w;
        zB[2].x += w2 * xB.x; zB[2].y += w2 * xB.y; zB[2].z += w2 * xB.z; zB[2].w += w2 * xB.w;
        zA[3].x += w3 * xA.x; zA[3].y += w3 * xA.y; zA[3].z += w3 * xA.z; zA[3].w += w3 * xA.w;
        zB[3].x += w3 * xB.x; zB[3].y += w3 * xB.y; zB[3].z += w3 * xB.z; zB[3].w += w3 * xB.w;
        // rotate pipeline
        em0 = em1; em1 = em2;
        ah = ahn; bh = bhn;
      }
    }

    // combine the two slots of each dir (lane ^ 16 stays within the dir half)
#pragma unroll
    for (int k = 0; k < 4; ++k) {
      zA[k].x += __shfl_xor(zA[k].x, 16);
      zA[k].y += __shfl_xor(zA[k].y, 16);
      zA[k].z += __shfl_xor(zA[k].z, 16);
      zA[k].w += __shfl_xor(zA[k].w, 16);
      zB[k].x += __shfl_xor(zB[k].x, 16);
      zB[k].y += __shfl_xor(zB[k].y, 16);
      zB[k].z += __shfl_xor(zB[k].z, 16);
      zB[k].w += __shfl_xor(zB[k].w, 16);
    }
    // write f16 z: byte = node*2048 + dir*1024 + k*256 + ((ll*16) ^ swz)
    if (slot == 0) {
      const int swz = (node & 7) << 4;
      char* zb = (char*)z16 + node * 2048 + dirg * 1024 + ((ll * 16) ^ swz);
#pragma unroll
      for (int k = 0; k < 4; ++k) {
        f16x8 o;
        o[0] = (_Float16)zA[k].x; o[1] = (_Float16)zA[k].y;
        o[2] = (_Float16)zA[k].z; o[3] = (_Float16)zA[k].w;
        o[4] = (_Float16)zB[k].x; o[5] = (_Float16)zB[k].y;
        o[6] = (_Float16)zB[k].z; o[7] = (_Float16)zB[k].w;
        *(f16x8*)(zb + k * 256) = o;
      }
    }
  }
  __syncthreads();

  // ---- phase 2: MFMA contraction; wave = k ----
  const int kk = w;
  const int lo16 = lane & 15;       // A row (node) / B col (o) / C col (o)
  const int kq = lane >> 4;         // k-chunk quarter
  {
    const int anode = lo16;
    const int aswz = (anode & 7) << 4;
    const char* zb = (const char*)z16 + anode * 2048 + kk * 256;
    f16x8 a[2][4];
#pragma unroll
    for (int d = 0; d < 2; ++d)
#pragma unroll
      for (int kc = 0; kc < 4; ++kc)
        a[d][kc] = *(const f16x8*)(zb + d * 1024 + ((kc * 64 + kq * 16) ^ aswz));

    f32x4 c0 = {0.f, 0.f, 0.f, 0.f};
    f32x4 c1 = {0.f, 0.f, 0.f, 0.f};
#pragma unroll
    for (int d = 0; d < 2; ++d)
#pragma unroll
      for (int kc = 0; kc < 4; ++kc) {
        const _Float16* mb = Mh + (((d * 4 + kk) * 2) * 16 + lo16) * 128 + kc * 32 + kq * 8;
        f16x8 b0 = *(const f16x8*)(mb);
        f16x8 b1 = *(const f16x8*)(mb + 2048);
        c0 = __builtin_amdgcn_mfma_f32_16x16x32_f16(a[d][kc], b0, c0, 0, 0, 0);
        c1 = __builtin_amdgcn_mfma_f32_16x16x32_f16(a[d][kc], b1, c1, 0, 0, 0);
      }

    const float third = 1.f / 3.f;
#pragma unroll
    for (int r = 0; r < 4; ++r) {
      // block-local node kq*4+r -> real id via the same mapping
      int tt = snodes[r * 4 * NTILES + kq * NTILES + blockIdx.x];
      size_t hb = (size_t)tt * C + kk * 32 + lo16;
      h[hb] = c0[r] * third;
      h[hb + 16] = c1[r] * third;
    }
  }
}

// ---------------- self-loop (MFMA) + bias + BN partial stats ----------------
// Persistent: 1280 blocks x 256 threads grid-stride over 16-row h tiles.
__global__ __launch_bounds__(256) void selfloop_kernel(
    float* __restrict__ h, const _Float16* __restrict__ LWh,
    const float* __restrict__ bias,
    float* __restrict__ bnsum, float* __restrict__ bnsq) {
  __shared__ __align__(16) _Float16 hf[2048];  // 16 rows x 256B, swizzled
  const int tid = threadIdx.x;
  const int w = tid >> 6, lane = tid & 63;
  const int row = tid >> 4;          // loader row 0..15
  const int l = tid & 15;            // loader 8-chunk
  const int lo16 = lane & 15;
  const int kq = lane >> 4;
  const float bv0 = bias[w * 32 + lo16];
  const float bv1 = bias[w * 32 + 16 + lo16];
  float s0 = 0.f, s1 = 0.f, sq0 = 0.f, sq1 = 0.f;

  const int aswz = (lo16 & 7) << 4;
  const int lswz = (row & 7) << 4;

  for (int tile = blockIdx.x; tile < NTILES; tile += gridDim.x) {
    // stage h tile as f16 (swizzled)
    {
      const float* hp = h + (size_t)(tile * 16 + row) * C + l * 8;
      float4 v0 = *(const float4*)(hp);
      float4 v1 = *(const float4*)(hp + 4);
      f16x8 o;
      o[0] = (_Float16)v0.x; o[1] = (_Float16)v0.y;
      o[2] = (_Float16)v0.z; o[3] = (_Float16)v0.w;
      o[4] = (_Float16)v1.x; o[5] = (_Float16)v1.y;
      o[6] = (_Float16)v1.z; o[7] = (_Float16)v1.w;
      *(f16x8*)((char*)hf + row * 256 + ((l * 16) ^ lswz)) = o;
    }
    __syncthreads();

    // MFMA: wave w -> output otiles 2w, 2w+1
    const char* zb = (const char*)hf + lo16 * 256;
    f32x4 c0 = {0.f, 0.f, 0.f, 0.f};
    f32x4 c1 = {0.f, 0.f, 0.f, 0.f};
#pragma unroll
    for (int kc = 0; kc < 4; ++kc) {
      f16x8 a = *(const f16x8*)(zb + ((kc * 64 + kq * 16) ^ aswz));
      const _Float16* mb = LWh + ((w * 2) * 16 + lo16) * 128 + kc * 32 + kq * 8;
      f16x8 b0 = *(const f16x8*)(mb);
      f16x8 b1 = *(const f16x8*)(mb + 2048);
      c0 = __builtin_amdgcn_mfma_f32_16x16x32_f16(a, b0, c0, 0, 0, 0);
      c1 = __builtin_amdgcn_mfma_f32_16x16x32_f16(a, b1, c1, 0, 0, 0);
    }

    // epilogue: h_new = h_orig(f32) + c + bias; BN stats
#pragma unroll
    for (int r = 0; r < 4; ++r) {
      int tt = tile * 16 + kq * 4 + r;
      size_t hb = (size_t)tt * C + w * 32 + lo16;
      float h0 = h[hb] + c0[r] + bv0;
      float h1 = h[hb + 16] + c1[r] + bv1;
      h[hb] = h0;
      h[hb + 16] = h1;
      s0 += h0; s1 += h1; sq0 += h0 * h0; sq1 += h1 * h1;
    }
    __syncthreads();  // done reading hf before next tile's writes
  }

  // reduce over kq (lanes lo16, +16, +32, +48), one atomic batch per column
  s0 += __shfl_xor(s0, 16); s0 += __shfl_xor(s0, 32);
  s1 += __shfl_xor(s1, 16); s1 += __shfl_xor(s1, 32);
  sq0 += __shfl_xor(sq0, 16); sq0 += __shfl_xor(sq0, 32);
  sq1 += __shfl_xor(sq1, 16); sq1 += __shfl_xor(sq1, 32);
  if (kq == 0) {
    atomicAdd(&bnsum[w * 32 + lo16], s0);
    atomicAdd(&bnsum[w * 32 + 16 + lo16], s1);
    atomicAdd(&bnsq[w * 32 + lo16], sq0);
    atomicAdd(&bnsq[w * 32 + 16 + lo16], sq1);
  }
}

// ---------------- BN finalize + tanh (fused) --------------------------------
__global__ void tanh_kernel(float* __restrict__ h,
                            const float* __restrict__ bnsum, const float* __restrict__ bnsq,
                            const float* __restrict__ gamma, const float* __restrict__ beta) {
  int idx = blockIdx.x * 256 + threadIdx.x;
  int base = idx * 4;
  if (base >= V * C) return;
  int j = base & 127;
  const float invV = 1.f / (float)V;
  float4 v = *(float4*)(h + base);
  float o[4] = {v.x, v.y, v.z, v.w};
#pragma unroll
  for (int cidx = 0; cidx < 4; ++cidx) {
    float mean = bnsum[j + cidx] * invV;
    float var = bnsq[j + cidx] * invV - mean * mean;
    float sc = gamma[j + cidx] * rsqrtf(var + 1e-5f);
    float sh = beta[j + cidx] - sc * mean;
    o[cidx] = tanhf(sc * o[cidx] + sh);
  }
  v.x = o[0]; v.y = o[1]; v.z = o[2]; v.w = o[3];
  *(float4*)(h + base) = v;
}

extern "C" void kernel_launch(void* const* d_in, const int* in_sizes, int n_in,
                              void* d_out, int out_size, void* d_ws, size_t ws_size,
                              hipStream_t stream) {
  const float* node_repr  = (const float*)d_in[0];
  const float* rel_repr   = (const float*)d_in[1];
  const int*   src        = (const int*)d_in[2];
  const int*   dst        = (const int*)d_in[3];
  const int*   etype      = (const int*)d_in[4];
  const float* norm       = (const float*)d_in[5];
  const float* node_w     = (const float*)d_in[6];
  const float* node_rel_w = (const float*)d_in[7];
  const float* in_w       = (const float*)d_in[8];
  const float* out_w      = (const float*)d_in[9];
  const float* att_w      = (const float*)d_in[10];
  const float* loop_rel   = (const float*)d_in[11];
  const float* loop_w     = (const float*)d_in[12];
  const float* w_rel      = (const float*)d_in[13];
  const float* bias       = (const float*)d_in[14];
  const float* bn_gamma   = (const float*)d_in[15];
  const float* bn_beta    = (const float*)d_in[16];

  float* out = (float*)d_out;
  float* h = out;                       // [V,128] accumulator, finalized in place
  float* rel_out = out + (size_t)V * C; // [474,128]

  // workspace layout (16B alignment maintained for int4/float4 users)
  int* cnt = (int*)d_ws;                // V
  int* cur_in = cnt + V;                // V
  int* cin = cur_in + V;                // V
  int* cur_out = cin + V;               // V
  float* bnsum = (float*)(cur_out + V); // 128
  float* bnsq = bnsum + 128;            // 128
  int* khist = (int*)(bnsq + 128);      // 256
  int* kcur = khist + 256;              // 256  -- zero region ends (4V+768)
  int* bsum = kcur + 256;               // 256
  int* snodes = bsum + 256;             // V
  int4* ninfo = (int4*)(snodes + V);    // V int4 (offset 5V+1280 ints, 16B ok)
  int2* em = (int2*)(ninfo + V);        // E int2
  float* qbuf = (float*)(em + E);       // 4V
  float* cbuf = qbuf + 4 * V;           // 512
  float* bbuf = cbuf + 512;             // 512
  _Float16* Mh = (_Float16*)(bbuf + 512);   // 32768 halves (f16 B-frag layout)
  _Float16* LWh = Mh + 32768;           // 16384 halves (selfloop B-frag)
  _Float16* nrp_h = LWh + 16384;        // V*C halves (12.8 MB)
  _Float16* rel_h = nrp_h + (size_t)V * C; // 474*128 halves

  hipMemsetAsync(cnt, 0, (size_t)(4 * V + 768) * 4, stream);

  prep_kernel<<<(1024 + 32768 + NREL2 * C / 8 + 16384 + 255) / 256, 256, 0, stream>>>(
      node_rel_w, node_w, in_w, out_w, att_w, rel_repr, loop_rel, loop_w,
      cbuf, bbuf, Mh, rel_h, LWh);
  qnode_kernel<<<NQBLK + RELBLK + HISTBLK, 256, 0, stream>>>(
      node_repr, bbuf, qbuf, nrp_h, rel_repr, w_rel, rel_out, dst, cnt, cin);
  scan_sum_kernel<<<NCHUNK, 256, 0, stream>>>(cnt, bsum);
  scan_apply_kernel<<<NCHUNK, 256, 0, stream>>>(cnt, cin, bsum, ninfo, khist);
  keyscan_kernel<<<1, 256, 0, stream>>>(khist);
  place_kernel<<<E / 256 + NCHUNK, 256, 0, stream>>>(dst, src, etype, norm, ninfo,
                                                     cur_in, cur_out, em,
                                                     khist, kcur, snodes);
  fused_kernel<<<NTILES, 256, 0, stream>>>(nrp_h, rel_h, ninfo, qbuf, cbuf, em,
                                           Mh, snodes, h);
  selfloop_kernel<<<1280, 256, 0, stream>>>(h, LWh, bias, bnsum, bnsq);
  tanh_kernel<<<(V * C / 4 + 255) / 256, 256, 0, stream>>>(h, bnsum, bnsq, bn_gamma, bn_beta);
}

// Round 17
// 479.735 us; speedup vs baseline: 1.3787x; 1.3787x over previous
//
#include <hip/hip_runtime.h>

namespace {
constexpr int V = 50000;
constexpr int E = 640000;
constexpr int HALF = 320000;
constexpr int NREL2 = 474;
constexpr int C = 128;
constexpr int NCHUNK = (V + 255) / 256; // 196
constexpr int NQBLK = V / 16;           // 3125 node-blocks in qnode
constexpr int RELBLK = (NREL2 + 1) / 2; // 237 relout blocks folded into qnode
constexpr int HISTBLK = E / 256;        // 2500 hist blocks folded into qnode
constexpr int NTILES = V / 16;          // 3125
}

typedef _Float16 h4 __attribute__((ext_vector_type(4)));
typedef _Float16 f16x8 __attribute__((ext_vector_type(8)));
typedef float f32x4 __attribute__((ext_vector_type(4)));

// ---- precompute: c[k,i], b[k,i], Mh + LWh (f16 frag layouts), rel_h cast ---
__global__ void prep_kernel(const float* __restrict__ nrw, const float* __restrict__ nw,
                            const float* __restrict__ inw, const float* __restrict__ outw,
                            const float* __restrict__ aw, const float* __restrict__ rel,
                            const float* __restrict__ lr, const float* __restrict__ lw,
                            float* __restrict__ cbuf, float* __restrict__ bbuf,
                            _Float16* __restrict__ Mh, _Float16* __restrict__ rel_h,
                            _Float16* __restrict__ LWh) {
  int tid = blockIdx.x * 256 + threadIdx.x;
  if (tid < 512) {
    int k = tid >> 7, i = tid & 127;
    float acc = 0.f;
    for (int d = 0; d < 32; ++d) acc += nrw[k*4096 + i*32 + d] * aw[d];
    cbuf[tid] = acc;
  } else if (tid < 1024) {
    int u = tid - 512; int k = u >> 7, i = u & 127;
    float acc = 0.f;
    for (int d = 0; d < 32; ++d) acc += nw[k*4096 + i*32 + d] * aw[32 + d];
    bbuf[u] = acc;
  } else if (tid < 1024 + 16384) {
    int u = tid - 1024; int k = u >> 12, rem = u & 4095, i = rem >> 5, o = rem & 31;
    float acc = 0.f;
    for (int d = 0; d < 32; ++d) acc += nrw[k*4096 + i*32 + d] * inw[k*1024 + d*32 + o];
    Mh[(((k) * 2 + (o >> 4)) * 16 + (o & 15)) * 128 + i] = (_Float16)acc;
  } else if (tid < 1024 + 32768) {
    int u = tid - 1024 - 16384; int k = u >> 12, rem = u & 4095, i = rem >> 5, o = rem & 31;
    float acc = 0.f;
    for (int d = 0; d < 32; ++d) acc += nrw[k*4096 + i*32 + d] * outw[k*1024 + d*32 + o];
    Mh[(((4 + k) * 2 + (o >> 4)) * 16 + (o & 15)) * 128 + i] = (_Float16)acc;
  } else if (tid < 1024 + 32768 + NREL2 * C / 8) {
    int u = tid - 1024 - 32768;  // 8-elem chunk of rel table
    const float4 v0 = *(const float4*)(rel + (size_t)u * 8);
    const float4 v1 = *(const float4*)(rel + (size_t)u * 8 + 4);
    f16x8 o;
    o[0] = (_Float16)v0.x; o[1] = (_Float16)v0.y;
    o[2] = (_Float16)v0.z; o[3] = (_Float16)v0.w;
    o[4] = (_Float16)v1.x; o[5] = (_Float16)v1.y;
    o[6] = (_Float16)v1.z; o[7] = (_Float16)v1.w;
    *(f16x8*)(rel_h + (size_t)u * 8) = o;
  } else if (tid < 1024 + 32768 + NREL2 * C / 8 + 16384) {
    int u = tid - 1024 - 32768 - NREL2 * C / 8;  // [o(128)][i(128)]
    int o = u >> 7, i = u & 127;
    float v = lr[i] * lw[i * C + o] * (1.f / 3.f);
    LWh[u] = (_Float16)v;
  }
}

// ---- q[t,k] = node_repr[t].b_k (16 lanes/node) + f16 node cast.
// Blocks [NQBLK, NQBLK+RELBLK): rel_out. Blocks beyond: edge histogram. -----
__global__ __launch_bounds__(256) void qnode_kernel(const float* __restrict__ nrp,
                                                    const float* __restrict__ bbuf,
                                                    float* __restrict__ qbuf,
                                                    _Float16* __restrict__ nrp_h,
                                                    const float* __restrict__ rel,
                                                    const float* __restrict__ wrel,
                                                    float* __restrict__ rel_out,
                                                    const int* __restrict__ dst,
                                                    int* __restrict__ cnt,
                                                    int* __restrict__ cin) {
  if (blockIdx.x >= NQBLK + RELBLK) {  // folded histogram
    int e = (blockIdx.x - NQBLK - RELBLK) * 256 + threadIdx.x;
    if (e < E) {
      int t = dst[e];
      atomicAdd(&cnt[t], 1);
      if (e < HALF) atomicAdd(&cin[t], 1);
    }
    return;
  }
  if (blockIdx.x >= NQBLK) {  // folded relout (block-uniform branch)
    __shared__ float rr2[2][128];
    const int bb = blockIdx.x - NQBLK;
    const int half = threadIdx.x >> 7;
    const int t128 = threadIdx.x & 127;
    const int row = bb * 2 + half;
    if (row < NREL2) rr2[half][t128] = rel[row * C + t128];
    __syncthreads();
    if (row < NREL2) {
      float acc = 0.f;
#pragma unroll 4
      for (int i = 0; i < C; ++i) acc += rr2[half][i] * wrel[i * C + t128];
      rel_out[row * C + t128] = acc;
    }
    return;
  }
  const int t = blockIdx.x * 16 + (threadIdx.x >> 4);
  const int l = threadIdx.x & 15;
  if (t >= V) return;
  const float* row = nrp + (size_t)t * C + l * 8;
  float4 a0 = *(const float4*)(row);
  float4 a1 = *(const float4*)(row + 4);
  {
    f16x8 o;
    o[0] = (_Float16)a0.x; o[1] = (_Float16)a0.y;
    o[2] = (_Float16)a0.z; o[3] = (_Float16)a0.w;
    o[4] = (_Float16)a1.x; o[5] = (_Float16)a1.y;
    o[6] = (_Float16)a1.z; o[7] = (_Float16)a1.w;
    *(f16x8*)(nrp_h + (size_t)t * C + l * 8) = o;
  }
  float p[4];
#pragma unroll
  for (int k = 0; k < 4; ++k) {
    const float* brow = bbuf + k * C + l * 8;
    float4 b0 = *(const float4*)(brow);
    float4 b1 = *(const float4*)(brow + 4);
    p[k] = a0.x * b0.x + a0.y * b0.y + a0.z * b0.z + a0.w * b0.w
         + a1.x * b1.x + a1.y * b1.y + a1.z * b1.z + a1.w * b1.w;
  }
#pragma unroll
  for (int m = 1; m < 16; m <<= 1) {
#pragma unroll
    for (int k = 0; k < 4; ++k) p[k] += __shfl_xor(p[k], m);
  }
  if (l == 0) *(float4*)(qbuf + 4 * (size_t)t) = make_float4(p[0], p[1], p[2], p[3]);
}

// ---------------- CSR scan ---------------------------------------------------
__global__ void scan_sum_kernel(const int* __restrict__ cnt, int* __restrict__ bsum) {
  __shared__ int sd[256];
  int tid = threadIdx.x;
  int idx = blockIdx.x * 256 + tid;
  int v = (idx < V) ? cnt[idx] : 0;
  sd[tid] = v; __syncthreads();
  for (int s = 128; s > 0; s >>= 1) {
    if (tid < s) sd[tid] += sd[tid + s];
    __syncthreads();
  }
  if (tid == 0) bsum[blockIdx.x] = sd[0];
}

// per-block scan + redundant top-scan (folds scan_top); ninfo = {off,deg,nin};
// also histogram nodes by nmax (for degree-balanced fused mapping)
__global__ void scan_apply_kernel(const int* __restrict__ cnt, const int* __restrict__ cin,
                                  const int* __restrict__ bsum, int4* __restrict__ ninfo,
                                  int* __restrict__ khist) {
  __shared__ int sd[256];
  __shared__ int sb[256];
  int tid = threadIdx.x;
  int idx = blockIdx.x * 256 + tid;
  // top-scan (inclusive) of block sums — redundant per block, cheap
  int b = (tid < NCHUNK) ? bsum[tid] : 0;
  sb[tid] = b; __syncthreads();
  for (int ofs = 1; ofs < 256; ofs <<= 1) {
    int t2 = (tid >= ofs) ? sb[tid - ofs] : 0;
    __syncthreads();
    sb[tid] += t2;
    __syncthreads();
  }
  const int blockoff = (blockIdx.x == 0) ? 0 : sb[blockIdx.x - 1];
  // per-node scan
  int v = (idx < V) ? cnt[idx] : 0;
  sd[tid] = v; __syncthreads();
  for (int ofs = 1; ofs < 256; ofs <<= 1) {
    int t2 = (tid >= ofs) ? sd[tid - ofs] : 0;
    __syncthreads();
    sd[tid] += t2;
    __syncthreads();
  }
  if (idx < V) {
    int ci = cin[idx];
    ninfo[idx] = make_int4(blockoff + sd[tid] - v, v, ci, 0);
    int key = min(max(ci, v - ci), 255);
    atomicAdd(&khist[key], 1);
  }
}

// exclusive scan of the 256-bin degree histogram (1 block)
__global__ void keyscan_kernel(int* __restrict__ khist) {
  __shared__ int sd[256];
  int tid = threadIdx.x;
  int v = khist[tid];
  sd[tid] = v; __syncthreads();
  for (int ofs = 1; ofs < 256; ofs <<= 1) {
    int t2 = (tid >= ofs) ? sd[tid - ofs] : 0;
    __syncthreads();
    sd[tid] += t2;
    __syncthreads();
  }
  khist[tid] = sd[tid] - v;  // exclusive
}

// place edges (in-edges first within node) + place nodes into degree-sorted
// order (snodes) with BLOCK-AGGREGATED counting sort: LDS per-key local
// histogram/rank, ONE global atomic per (block, key) — kills the same-address
// contention that round-15's per-node kcur atomics caused (217us stall).
__global__ void place_kernel(const int* __restrict__ dst, const int* __restrict__ src,
                             const int* __restrict__ etype, const float* __restrict__ norm,
                             const int4* __restrict__ ninfo,
                             int* __restrict__ cur_in, int* __restrict__ cur_out,
                             int2* __restrict__ em,
                             const int* __restrict__ khist, int* __restrict__ kcur,
                             int* __restrict__ snodes) {
  if (blockIdx.x >= E / 256) {  // node placement (degree-sorted, aggregated)
    __shared__ int lhist[256];
    __shared__ int lbase[256];
    const int t = (blockIdx.x - E / 256) * 256 + threadIdx.x;
    lhist[threadIdx.x] = 0;
    __syncthreads();
    int key = 0, lrank = 0;
    const bool valid = (t < V);
    if (valid) {
      int4 nf = ninfo[t];
      key = min(max(nf.z, nf.y - nf.z), 255);
      lrank = atomicAdd(&lhist[key], 1);  // LDS atomic: local rank
    }
    __syncthreads();
    const int lc = lhist[threadIdx.x];
    if (lc > 0) lbase[threadIdx.x] = atomicAdd(&kcur[threadIdx.x], lc);
    __syncthreads();
    if (valid) {
      snodes[khist[key] + lbase[key] + lrank] = t;
    }
    return;
  }
  int e = blockIdx.x * 256 + threadIdx.x;
  {
    int t = dst[e];
    int4 nf = ninfo[t];
    int pos;
    if (e < HALF) {
      pos = nf.x + atomicAdd(&cur_in[t], 1);
    } else {
      pos = nf.x + nf.z + atomicAdd(&cur_out[t], 1);
    }
    em[pos] = make_int2(src[e] | (etype[e] << 16), __float_as_int(norm[e]));
  }
}

// ---------------- fused: gather + attention + z accum + MFMA ----------------
// Round-9 config + degree-balanced node mapping: block b, wave w, slot nn
// processes sorted-rank nn*4*NTILES + w*NTILES + b — every wave and every
// block spans the degree distribution uniformly (no barrier/drain waste).
__global__ __launch_bounds__(256) void fused_kernel(
    const _Float16* __restrict__ nrp_h, const _Float16* __restrict__ rel_h,
    const int4* __restrict__ ninfo, const float* __restrict__ qbuf,
    const float* __restrict__ cbuf, const int2* __restrict__ em,
    const _Float16* __restrict__ Mh, const int* __restrict__ snodes,
    float* __restrict__ h) {
  __shared__ __align__(16) _Float16 z16[16384];  // 16 nodes x 2048B, swizzled
  const int w = threadIdx.x >> 6;
  const int lane = threadIdx.x & 63;
  const int dirg = lane >> 5;        // 0: in-edges, 1: out-edges
  const int slot = (lane >> 4) & 1;  // edge slot within dir
  const int ll = lane & 15;          // 8-channel chunk
  const int ch0 = ll * 8;

  // c_k chunks: register-resident (8 floats per k)
  float4 ckA[4], ckB[4];
#pragma unroll
  for (int k = 0; k < 4; ++k) {
    ckA[k] = *(const float4*)(cbuf + k * C + ch0);
    ckB[k] = *(const float4*)(cbuf + k * C + ch0 + 4);
  }

  // ---- phase 1: per-node edge loop, 4 edges per wave-iteration ----
  for (int nn = 0; nn < 4; ++nn) {
    const int node = w * 4 + nn;               // block-local 0..15
    const int t = snodes[nn * 4 * NTILES + w * NTILES + blockIdx.x];
    const int4 nfo = ninfo[t];
    const int start = nfo.x, deg = nfo.y, ni = nfo.z;
    const float4 q4 = *(const float4*)(qbuf + 4 * (size_t)t);
    const int sidx = dirg ? ni : 0;
    const int nmy = dirg ? (deg - ni) : ni;
    const int nmax = max(ni, deg - ni);        // wave-uniform

    float4 zA[4], zB[4];
#pragma unroll
    for (int k = 0; k < 4; ++k) {
      zA[k] = make_float4(0.f, 0.f, 0.f, 0.f);
      zB[k] = make_float4(0.f, 0.f, 0.f, 0.f);
    }

    if (nmax > 0) {
      // stage: em0 -> current (j), em1 -> next (j+2); rows for j in flight
      int2 em0 = em[start + min(sidx + slot, deg - 1)];
      int2 em1 = em[start + min(sidx + 2 + slot, deg - 1)];
      f16x8 ah = *(const f16x8*)(nrp_h + (size_t)(em0.x & 0xFFFF) * C + ch0);
      f16x8 bh = *(const f16x8*)(rel_h + (size_t)((em0.x >> 16) & 0x1FF) * C + ch0);

      for (int j = 0; j < nmax; j += 2) {
        // stage meta for j+4 (no dependencies; wave-uniform condition)
        int2 em2 = em1;
        if (j + 4 < nmax) em2 = em[start + min(sidx + j + 4 + slot, deg - 1)];
        // stage rows for j+2 using em1 (arrived a full iteration ago)
        f16x8 ahn = ah, bhn = bh;
        if (j + 2 < nmax) {
          ahn = *(const f16x8*)(nrp_h + (size_t)(em1.x & 0xFFFF) * C + ch0);
          bhn = *(const f16x8*)(rel_h + (size_t)((em1.x >> 16) & 0x1FF) * C + ch0);
        }
        // compute current edge (j + slot): x = a*b in f32
        float4 xA, xB;
        xA.x = (float)ah[0] * (float)bh[0];
        xA.y = (float)ah[1] * (float)bh[1];
        xA.z = (float)ah[2] * (float)bh[2];
        xA.w = (float)ah[3] * (float)bh[3];
        xB.x = (float)ah[4] * (float)bh[4];
        xB.y = (float)ah[5] * (float)bh[5];
        xB.z = (float)ah[6] * (float)bh[6];
        xB.w = (float)ah[7] * (float)bh[7];
        float p0 = xA.x * ckA[0].x + xA.y * ckA[0].y + xA.z * ckA[0].z + xA.w * ckA[0].w
                 + xB.x * ckB[0].x + xB.y * ckB[0].y + xB.z * ckB[0].z + xB.w * ckB[0].w;
        float p1 = xA.x * ckA[1].x + xA.y * ckA[1].y + xA.z * ckA[1].z + xA.w * ckA[1].w
                 + xB.x * ckB[1].x + xB.y * ckB[1].y + xB.z * ckB[1].z + xB.w * ckB[1].w;
        float p2 = xA.x * ckA[2].x + xA.y * ckA[2].y + xA.z * ckA[2].z + xA.w * ckA[2].w
                 + xB.x * ckB[2].x + xB.y * ckB[2].y + xB.z * ckB[2].z + xB.w * ckB[2].w;
        float p3 = xA.x * ckA[3].x + xA.y * ckA[3].y + xA.z * ckA[3].z + xA.w * ckA[3].w
                 + xB.x * ckB[3].x + xB.y * ckB[3].y + xB.z * ckB[3].z + xB.w * ckB[3].w;
#pragma unroll
        for (int m = 1; m < 16; m <<= 1) {
          p0 += __shfl_xor(p0, m);
          p1 += __shfl_xor(p1, m);
          p2 += __shfl_xor(p2, m);
          p3 += __shfl_xor(p3, m);
        }
        // softmax (no max-sub: logits are relu'd and small for this model)
        float l0 = fmaxf(p0 + q4.x, 0.f);
        float l1 = fmaxf(p1 + q4.y, 0.f);
        float l2 = fmaxf(p2 + q4.z, 0.f);
        float l3 = fmaxf(p3 + q4.w, 0.f);
        float e0f = __expf(l0), e1f = __expf(l1);
        float e2f = __expf(l2), e3f = __expf(l3);
        float nr = __int_as_float(em0.y);
        float inv = ((j + slot) < nmy) ? (nr / (e0f + e1f + e2f + e3f)) : 0.f;
        float w0 = e0f * inv, w1 = e1f * inv, w2 = e2f * inv, w3 = e3f * inv;
        zA[0].x += w0 * xA.x; zA[0].y += w0 * xA.y; zA[0].z += w0 * xA.z; zA[0].w += w0 * xA.w;
        zB[0].x += w0 * xB.x; zB[0].y += w0 * xB.y; zB[0].z += w0 * xB.z; zB[0].w += w0 * xB.w;
        zA[1].x += w1 * xA.x; zA[1].y += w1 * xA.y; zA[1].z += w1 * xA.z; zA[1].w += w1 * xA.w;
        zB[1].x += w1 * xB.x; zB[1].y += w1 * xB.y; zB[1].z += w1 * xB.z; zB[1].w += w1 * xB.w;
        zA[2].x += w2 * xA.x; zA[2].y += w2 * xA.y; zA[2].z += w2 * xA.z; zA[2].w += w2 * xA.w;
        zB[2].x += w2 * xB.x; zB[2].y += w2 * xB.y; zB[2].z += w2 * xB.z; zB[2].w += w2 * xB.w;
        zA[3].x += w3 * xA.x; zA[3].y += w3 * xA.y; zA[3].z += w3 * xA.z; zA[3].w += w3 * xA.w;
        zB[3].x += w3 * xB.x; zB[3].y += w3 * xB.y; zB[3].z += w3 * xB.z; zB[3].w += w3 * xB.w;
        // rotate pipeline
        em0 = em1; em1 = em2;
        ah = ahn; bh = bhn;
      }
    }

    // combine the two slots of each dir (lane ^ 16 stays within the dir half)
#pragma unroll
    for (int k = 0; k < 4; ++k) {
      zA[k].x += __shfl_xor(zA[k].x, 16);
      zA[k].y += __shfl_xor(zA[k].y, 16);
      zA[k].z += __shfl_xor(zA[k].z, 16);
      zA[k].w += __shfl_xor(zA[k].w, 16);
      zB[k].x += __shfl_xor(zB[k].x, 16);
      zB[k].y += __shfl_xor(zB[k].y, 16);
      zB[k].z += __shfl_xor(zB[k].z, 16);
      zB[k].w += __shfl_xor(zB[k].w, 16);
    }
    // write f16 z: byte = node*2048 + dir*1024 + k*256 + ((ll*16) ^ swz)
    if (slot == 0) {
      const int swz = (node & 7) << 4;
      char* zb = (char*)z16 + node * 2048 + dirg * 1024 + ((ll * 16) ^ swz);
#pragma unroll
      for (int k = 0; k < 4; ++k) {
        f16x8 o;
        o[0] = (_Float16)zA[k].x; o[1] = (_Float16)zA[k].y;
        o[2] = (_Float16)zA[k].z; o[3] = (_Float16)zA[k].w;
        o[4] = (_Float16)zB[k].x; o[5] = (_Float16)zB[k].y;
        o[6] = (_Float16)zB[k].z; o[7] = (_Float16)zB[k].w;
        *(f16x8*)(zb + k * 256) = o;
      }
    }
  }
  __syncthreads();

  // ---- phase 2: MFMA contraction; wave = k ----
  const int kk = w;
  const int lo16 = lane & 15;       // A row (node) / B col (o) / C col (o)
  const int kq = lane >> 4;         // k-chunk quarter
  {
    const int anode = lo16;
    const int aswz = (anode & 7) << 4;
    const char* zb = (const char*)z16 + anode * 2048 + kk * 256;
    f16x8 a[2][4];
#pragma unroll
    for (int d = 0; d < 2; ++d)
#pragma unroll
      for (int kc = 0; kc < 4; ++kc)
        a[d][kc] = *(const f16x8*)(zb + d * 1024 + ((kc * 64 + kq * 16) ^ aswz));

    f32x4 c0 = {0.f, 0.f, 0.f, 0.f};
    f32x4 c1 = {0.f, 0.f, 0.f, 0.f};
#pragma unroll
    for (int d = 0; d < 2; ++d)
#pragma unroll
      for (int kc = 0; kc < 4; ++kc) {
        const _Float16* mb = Mh + (((d * 4 + kk) * 2) * 16 + lo16) * 128 + kc * 32 + kq * 8;
        f16x8 b0 = *(const f16x8*)(mb);
        f16x8 b1 = *(const f16x8*)(mb + 2048);
        c0 = __builtin_amdgcn_mfma_f32_16x16x32_f16(a[d][kc], b0, c0, 0, 0, 0);
        c1 = __builtin_amdgcn_mfma_f32_16x16x32_f16(a[d][kc], b1, c1, 0, 0, 0);
      }

    const float third = 1.f / 3.f;
#pragma unroll
    for (int r = 0; r < 4; ++r) {
      // block-local node kq*4+r -> real id via the same mapping
      int tt = snodes[r * 4 * NTILES + kq * NTILES + blockIdx.x];
      size_t hb = (size_t)tt * C + kk * 32 + lo16;
      h[hb] = c0[r] * third;
      h[hb + 16] = c1[r] * third;
    }
  }
}

// ---------------- self-loop (MFMA) + bias + BN partial stats ----------------
// Persistent: 1280 blocks x 256 threads grid-stride over 16-row h tiles.
__global__ __launch_bounds__(256) void selfloop_kernel(
    float* __restrict__ h, const _Float16* __restrict__ LWh,
    const float* __restrict__ bias,
    float* __restrict__ bnsum, float* __restrict__ bnsq) {
  __shared__ __align__(16) _Float16 hf[2048];  // 16 rows x 256B, swizzled
  const int tid = threadIdx.x;
  const int w = tid >> 6, lane = tid & 63;
  const int row = tid >> 4;          // loader row 0..15
  const int l = tid & 15;            // loader 8-chunk
  const int lo16 = lane & 15;
  const int kq = lane >> 4;
  const float bv0 = bias[w * 32 + lo16];
  const float bv1 = bias[w * 32 + 16 + lo16];
  float s0 = 0.f, s1 = 0.f, sq0 = 0.f, sq1 = 0.f;

  const int aswz = (lo16 & 7) << 4;
  const int lswz = (row & 7) << 4;

  for (int tile = blockIdx.x; tile < NTILES; tile += gridDim.x) {
    // stage h tile as f16 (swizzled)
    {
      const float* hp = h + (size_t)(tile * 16 + row) * C + l * 8;
      float4 v0 = *(const float4*)(hp);
      float4 v1 = *(const float4*)(hp + 4);
      f16x8 o;
      o[0] = (_Float16)v0.x; o[1] = (_Float16)v0.y;
      o[2] = (_Float16)v0.z; o[3] = (_Float16)v0.w;
      o[4] = (_Float16)v1.x; o[5] = (_Float16)v1.y;
      o[6] = (_Float16)v1.z; o[7] = (_Float16)v1.w;
      *(f16x8*)((char*)hf + row * 256 + ((l * 16) ^ lswz)) = o;
    }
    __syncthreads();

    // MFMA: wave w -> output otiles 2w, 2w+1
    const char* zb = (const char*)hf + lo16 * 256;
    f32x4 c0 = {0.f, 0.f, 0.f, 0.f};
    f32x4 c1 = {0.f, 0.f, 0.f, 0.f};
#pragma unroll
    for (int kc = 0; kc < 4; ++kc) {
      f16x8 a = *(const f16x8*)(zb + ((kc * 64 + kq * 16) ^ aswz));
      const _Float16* mb = LWh + ((w * 2) * 16 + lo16) * 128 + kc * 32 + kq * 8;
      f16x8 b0 = *(const f16x8*)(mb);
      f16x8 b1 = *(const f16x8*)(mb + 2048);
      c0 = __builtin_amdgcn_mfma_f32_16x16x32_f16(a, b0, c0, 0, 0, 0);
      c1 = __builtin_amdgcn_mfma_f32_16x16x32_f16(a, b1, c1, 0, 0, 0);
    }

    // epilogue: h_new = h_orig(f32) + c + bias; BN stats
#pragma unroll
    for (int r = 0; r < 4; ++r) {
      int tt = tile * 16 + kq * 4 + r;
      size_t hb = (size_t)tt * C + w * 32 + lo16;
      float h0 = h[hb] + c0[r] + bv0;
      float h1 = h[hb + 16] + c1[r] + bv1;
      h[hb] = h0;
      h[hb + 16] = h1;
      s0 += h0; s1 += h1; sq0 += h0 * h0; sq1 += h1 * h1;
    }
    __syncthreads();  // done reading hf before next tile's writes
  }

  // reduce over kq (lanes lo16, +16, +32, +48), one atomic batch per column
  s0 += __shfl_xor(s0, 16); s0 += __shfl_xor(s0, 32);
  s1 += __shfl_xor(s1, 16); s1 += __shfl_xor(s1, 32);
  sq0 += __shfl_xor(sq0, 16); sq0 += __shfl_xor(sq0, 32);
  sq1 += __shfl_xor(sq1, 16); sq1 += __shfl_xor(sq1, 32);
  if (kq == 0) {
    atomicAdd(&bnsum[w * 32 + lo16], s0);
    atomicAdd(&bnsum[w * 32 + 16 + lo16], s1);
    atomicAdd(&bnsq[w * 32 + lo16], sq0);
    atomicAdd(&bnsq[w * 32 + 16 + lo16], sq1);
  }
}

// ---------------- BN finalize + tanh (fused) --------------------------------
__global__ void tanh_kernel(float* __restrict__ h,
                            const float* __restrict__ bnsum, const float* __restrict__ bnsq,
                            const float* __restrict__ gamma, const float* __restrict__ beta) {
  int idx = blockIdx.x * 256 + threadIdx.x;
  int base = idx * 4;
  if (base >= V * C) return;
  int j = base & 127;
  const float invV = 1.f / (float)V;
  float4 v = *(float4*)(h + base);
  float o[4] = {v.x, v.y, v.z, v.w};
#pragma unroll
  for (int cidx = 0; cidx < 4; ++cidx) {
    float mean = bnsum[j + cidx] * invV;
    float var = bnsq[j + cidx] * invV - mean * mean;
    float sc = gamma[j + cidx] * rsqrtf(var + 1e-5f);
    float sh = beta[j + cidx] - sc * mean;
    o[cidx] = tanhf(sc * o[cidx] + sh);
  }
  v.x = o[0]; v.y = o[1]; v.z = o[2]; v.w = o[3];
  *(float4*)(h + base) = v;
}

extern "C" void kernel_launch(void* const* d_in, const int* in_sizes, int n_in,
                              void* d_out, int out_size, void* d_ws, size_t ws_size,
                              hipStream_t stream) {
  const float* node_repr  = (const float*)d_in[0];
  const float* rel_repr   = (const float*)d_in[1];
  const int*   src        = (const int*)d_in[2];
  const int*   dst        = (const int*)d_in[3];
  const int*   etype      = (const int*)d_in[4];
  const float* norm       = (const float*)d_in[5];
  const float* node_w     = (const float*)d_in[6];
  const float* node_rel_w = (const float*)d_in[7];
  const float* in_w       = (const float*)d_in[8];
  const float* out_w      = (const float*)d_in[9];
  const float* att_w      = (const float*)d_in[10];
  const float* loop_rel   = (const float*)d_in[11];
  const float* loop_w     = (const float*)d_in[12];
  const float* w_rel      = (const float*)d_in[13];
  const float* bias       = (const float*)d_in[14];
  const float* bn_gamma   = (const float*)d_in[15];
  const float* bn_beta    = (const float*)d_in[16];

  float* out = (float*)d_out;
  float* h = out;                       // [V,128] accumulator, finalized in place
  float* rel_out = out + (size_t)V * C; // [474,128]

  // workspace layout (16B alignment maintained for int4/float4 users)
  int* cnt = (int*)d_ws;                // V
  int* cur_in = cnt + V;                // V
  int* cin = cur_in + V;                // V
  int* cur_out = cin + V;               // V
  float* bnsum = (float*)(cur_out + V); // 128
  float* bnsq = bnsum + 128;            // 128
  int* khist = (int*)(bnsq + 128);      // 256
  int* kcur = khist + 256;              // 256  -- zero region ends (4V+768)
  int* bsum = kcur + 256;               // 256
  int* snodes = bsum + 256;             // V
  int4* ninfo = (int4*)(snodes + V);    // V int4 (offset 5V+1280 ints, 16B ok)
  int2* em = (int2*)(ninfo + V);        // E int2
  float* qbuf = (float*)(em + E);       // 4V
  float* cbuf = qbuf + 4 * V;           // 512
  float* bbuf = cbuf + 512;             // 512
  _Float16* Mh = (_Float16*)(bbuf + 512);   // 32768 halves (f16 B-frag layout)
  _Float16* LWh = Mh + 32768;           // 16384 halves (selfloop B-frag)
  _Float16* nrp_h = LWh + 16384;        // V*C halves (12.8 MB)
  _Float16* rel_h = nrp_h + (size_t)V * C; // 474*128 halves

  hipMemsetAsync(cnt, 0, (size_t)(4 * V + 768) * 4, stream);

  prep_kernel<<<(1024 + 32768 + NREL2 * C / 8 + 16384 + 255) / 256, 256, 0, stream>>>(
      node_rel_w, node_w, in_w, out_w, att_w, rel_repr, loop_rel, loop_w,
      cbuf, bbuf, Mh, rel_h, LWh);
  qnode_kernel<<<NQBLK + RELBLK + HISTBLK, 256, 0, stream>>>(
      node_repr, bbuf, qbuf, nrp_h, rel_repr, w_rel, rel_out, dst, cnt, cin);
  scan_sum_kernel<<<NCHUNK, 256, 0, stream>>>(cnt, bsum);
  scan_apply_kernel<<<NCHUNK, 256, 0, stream>>>(cnt, cin, bsum, ninfo, khist);
  keyscan_kernel<<<1, 256, 0, stream>>>(khist);
  place_kernel<<<E / 256 + NCHUNK, 256, 0, stream>>>(dst, src, etype, norm, ninfo,
                                                     cur_in, cur_out, em,
                                                     khist, kcur, snodes);
  fused_kernel<<<NTILES, 256, 0, stream>>>(nrp_h, rel_h, ninfo, qbuf, cbuf, em,
                                           Mh, snodes, h);
  selfloop_kernel<<<1280, 256, 0, stream>>>(h, LWh, bias, bnsum, bnsq);
  tanh_kernel<<<(V * C / 4 + 255) / 256, 256, 0, stream>>>(h, bnsum, bnsq, bn_gamma, bn_beta);
}

// Round 18
// 291.693 us; speedup vs baseline: 2.2674x; 1.6447x over previous
//
#include <hip/hip_runtime.h>

namespace {
constexpr int V = 50000;
constexpr int E = 640000;
constexpr int HALF = 320000;
constexpr int NREL2 = 474;
constexpr int C = 128;
constexpr int NCHUNK = (V + 255) / 256; // 196
constexpr int NQBLK = V / 16;           // 3125 node-blocks in qnode
constexpr int RELBLK = (NREL2 + 1) / 2; // 237 relout blocks folded into qnode
constexpr int HISTBLK = E / 256;        // 2500 hist blocks folded into qnode
constexpr int NTILES = V / 16;          // 3125
}

typedef _Float16 h4 __attribute__((ext_vector_type(4)));
typedef _Float16 f16x8 __attribute__((ext_vector_type(8)));
typedef float f32x4 __attribute__((ext_vector_type(4)));

// ---- precompute: c[k,i], b[k,i], Mh + LWh (f16 frag layouts), rel_h cast ---
__global__ void prep_kernel(const float* __restrict__ nrw, const float* __restrict__ nw,
                            const float* __restrict__ inw, const float* __restrict__ outw,
                            const float* __restrict__ aw, const float* __restrict__ rel,
                            const float* __restrict__ lr, const float* __restrict__ lw,
                            float* __restrict__ cbuf, float* __restrict__ bbuf,
                            _Float16* __restrict__ Mh, _Float16* __restrict__ rel_h,
                            _Float16* __restrict__ LWh) {
  int tid = blockIdx.x * 256 + threadIdx.x;
  if (tid < 512) {
    int k = tid >> 7, i = tid & 127;
    float acc = 0.f;
    for (int d = 0; d < 32; ++d) acc += nrw[k*4096 + i*32 + d] * aw[d];
    cbuf[tid] = acc;
  } else if (tid < 1024) {
    int u = tid - 512; int k = u >> 7, i = u & 127;
    float acc = 0.f;
    for (int d = 0; d < 32; ++d) acc += nw[k*4096 + i*32 + d] * aw[32 + d];
    bbuf[u] = acc;
  } else if (tid < 1024 + 16384) {
    int u = tid - 1024; int k = u >> 12, rem = u & 4095, i = rem >> 5, o = rem & 31;
    float acc = 0.f;
    for (int d = 0; d < 32; ++d) acc += nrw[k*4096 + i*32 + d] * inw[k*1024 + d*32 + o];
    Mh[(((k) * 2 + (o >> 4)) * 16 + (o & 15)) * 128 + i] = (_Float16)acc;
  } else if (tid < 1024 + 32768) {
    int u = tid - 1024 - 16384; int k = u >> 12, rem = u & 4095, i = rem >> 5, o = rem & 31;
    float acc = 0.f;
    for (int d = 0; d < 32; ++d) acc += nrw[k*4096 + i*32 + d] * outw[k*1024 + d*32 + o];
    Mh[(((4 + k) * 2 + (o >> 4)) * 16 + (o & 15)) * 128 + i] = (_Float16)acc;
  } else if (tid < 1024 + 32768 + NREL2 * C / 8) {
    int u = tid - 1024 - 32768;  // 8-elem chunk of rel table
    const float4 v0 = *(const float4*)(rel + (size_t)u * 8);
    const float4 v1 = *(const float4*)(rel + (size_t)u * 8 + 4);
    f16x8 o;
    o[0] = (_Float16)v0.x; o[1] = (_Float16)v0.y;
    o[2] = (_Float16)v0.z; o[3] = (_Float16)v0.w;
    o[4] = (_Float16)v1.x; o[5] = (_Float16)v1.y;
    o[6] = (_Float16)v1.z; o[7] = (_Float16)v1.w;
    *(f16x8*)(rel_h + (size_t)u * 8) = o;
  } else if (tid < 1024 + 32768 + NREL2 * C / 8 + 16384) {
    int u = tid - 1024 - 32768 - NREL2 * C / 8;  // [o(128)][i(128)]
    int o = u >> 7, i = u & 127;
    float v = lr[i] * lw[i * C + o] * (1.f / 3.f);
    LWh[u] = (_Float16)v;
  }
}

// ---- q[t,k] = node_repr[t].b_k (16 lanes/node) + f16 node cast.
// Blocks [NQBLK, NQBLK+RELBLK): rel_out. Blocks beyond: edge histogram. -----
__global__ __launch_bounds__(256) void qnode_kernel(const float* __restrict__ nrp,
                                                    const float* __restrict__ bbuf,
                                                    float* __restrict__ qbuf,
                                                    _Float16* __restrict__ nrp_h,
                                                    const float* __restrict__ rel,
                                                    const float* __restrict__ wrel,
                                                    float* __restrict__ rel_out,
                                                    const int* __restrict__ dst,
                                                    int* __restrict__ cnt,
                                                    int* __restrict__ cin) {
  if (blockIdx.x >= NQBLK + RELBLK) {  // folded histogram
    int e = (blockIdx.x - NQBLK - RELBLK) * 256 + threadIdx.x;
    if (e < E) {
      int t = dst[e];
      atomicAdd(&cnt[t], 1);
      if (e < HALF) atomicAdd(&cin[t], 1);
    }
    return;
  }
  if (blockIdx.x >= NQBLK) {  // folded relout (block-uniform branch)
    __shared__ float rr2[2][128];
    const int bb = blockIdx.x - NQBLK;
    const int half = threadIdx.x >> 7;
    const int t128 = threadIdx.x & 127;
    const int row = bb * 2 + half;
    if (row < NREL2) rr2[half][t128] = rel[row * C + t128];
    __syncthreads();
    if (row < NREL2) {
      float acc = 0.f;
#pragma unroll 4
      for (int i = 0; i < C; ++i) acc += rr2[half][i] * wrel[i * C + t128];
      rel_out[row * C + t128] = acc;
    }
    return;
  }
  const int t = blockIdx.x * 16 + (threadIdx.x >> 4);
  const int l = threadIdx.x & 15;
  if (t >= V) return;
  const float* row = nrp + (size_t)t * C + l * 8;
  float4 a0 = *(const float4*)(row);
  float4 a1 = *(const float4*)(row + 4);
  {
    f16x8 o;
    o[0] = (_Float16)a0.x; o[1] = (_Float16)a0.y;
    o[2] = (_Float16)a0.z; o[3] = (_Float16)a0.w;
    o[4] = (_Float16)a1.x; o[5] = (_Float16)a1.y;
    o[6] = (_Float16)a1.z; o[7] = (_Float16)a1.w;
    *(f16x8*)(nrp_h + (size_t)t * C + l * 8) = o;
  }
  float p[4];
#pragma unroll
  for (int k = 0; k < 4; ++k) {
    const float* brow = bbuf + k * C + l * 8;
    float4 b0 = *(const float4*)(brow);
    float4 b1 = *(const float4*)(brow + 4);
    p[k] = a0.x * b0.x + a0.y * b0.y + a0.z * b0.z + a0.w * b0.w
         + a1.x * b1.x + a1.y * b1.y + a1.z * b1.z + a1.w * b1.w;
  }
#pragma unroll
  for (int m = 1; m < 16; m <<= 1) {
#pragma unroll
    for (int k = 0; k < 4; ++k) p[k] += __shfl_xor(p[k], m);
  }
  if (l == 0) *(float4*)(qbuf + 4 * (size_t)t) = make_float4(p[0], p[1], p[2], p[3]);
}

// ---------------- CSR scan ---------------------------------------------------
__global__ void scan_sum_kernel(const int* __restrict__ cnt, int* __restrict__ bsum) {
  __shared__ int sd[256];
  int tid = threadIdx.x;
  int idx = blockIdx.x * 256 + tid;
  int v = (idx < V) ? cnt[idx] : 0;
  sd[tid] = v; __syncthreads();
  for (int s = 128; s > 0; s >>= 1) {
    if (tid < s) sd[tid] += sd[tid + s];
    __syncthreads();
  }
  if (tid == 0) bsum[blockIdx.x] = sd[0];
}

// per-block scan + redundant top-scan (folds scan_top); ninfo = {off,deg,nin};
// degree histogram is LDS-AGGREGATED: one global atomic per (block, key) —
// round-16's per-node khist atomics serialized on hot bins (193us stall).
__global__ void scan_apply_kernel(const int* __restrict__ cnt, const int* __restrict__ cin,
                                  const int* __restrict__ bsum, int4* __restrict__ ninfo,
                                  int* __restrict__ khist) {
  __shared__ int sd[256];
  __shared__ int sb[256];
  __shared__ int lh[256];
  int tid = threadIdx.x;
  int idx = blockIdx.x * 256 + tid;
  lh[tid] = 0;
  // top-scan (inclusive) of block sums — redundant per block, cheap
  int b = (tid < NCHUNK) ? bsum[tid] : 0;
  sb[tid] = b; __syncthreads();
  for (int ofs = 1; ofs < 256; ofs <<= 1) {
    int t2 = (tid >= ofs) ? sb[tid - ofs] : 0;
    __syncthreads();
    sb[tid] += t2;
    __syncthreads();
  }
  const int blockoff = (blockIdx.x == 0) ? 0 : sb[blockIdx.x - 1];
  // per-node scan
  int v = (idx < V) ? cnt[idx] : 0;
  sd[tid] = v; __syncthreads();
  for (int ofs = 1; ofs < 256; ofs <<= 1) {
    int t2 = (tid >= ofs) ? sd[tid - ofs] : 0;
    __syncthreads();
    sd[tid] += t2;
    __syncthreads();
  }
  if (idx < V) {
    int ci = cin[idx];
    ninfo[idx] = make_int4(blockoff + sd[tid] - v, v, ci, 0);
    int key = min(max(ci, v - ci), 255);
    atomicAdd(&lh[key], 1);  // LDS atomic (local aggregation)
  }
  __syncthreads();
  const int lc = lh[tid];
  if (lc > 0) atomicAdd(&khist[tid], lc);  // one global atomic per (block,key)
}

// exclusive scan of the 256-bin degree histogram (1 block)
__global__ void keyscan_kernel(int* __restrict__ khist) {
  __shared__ int sd[256];
  int tid = threadIdx.x;
  int v = khist[tid];
  sd[tid] = v; __syncthreads();
  for (int ofs = 1; ofs < 256; ofs <<= 1) {
    int t2 = (tid >= ofs) ? sd[tid - ofs] : 0;
    __syncthreads();
    sd[tid] += t2;
    __syncthreads();
  }
  khist[tid] = sd[tid] - v;  // exclusive
}

// place edges (in-edges first within node) + place nodes into degree-sorted
// order (snodes) with BLOCK-AGGREGATED counting sort (LDS local rank, one
// global atomic per (block, key)).
__global__ void place_kernel(const int* __restrict__ dst, const int* __restrict__ src,
                             const int* __restrict__ etype, const float* __restrict__ norm,
                             const int4* __restrict__ ninfo,
                             int* __restrict__ cur_in, int* __restrict__ cur_out,
                             int2* __restrict__ em,
                             const int* __restrict__ khist, int* __restrict__ kcur,
                             int* __restrict__ snodes) {
  if (blockIdx.x >= E / 256) {  // node placement (degree-sorted, aggregated)
    __shared__ int lhist[256];
    __shared__ int lbase[256];
    const int t = (blockIdx.x - E / 256) * 256 + threadIdx.x;
    lhist[threadIdx.x] = 0;
    __syncthreads();
    int key = 0, lrank = 0;
    const bool valid = (t < V);
    if (valid) {
      int4 nf = ninfo[t];
      key = min(max(nf.z, nf.y - nf.z), 255);
      lrank = atomicAdd(&lhist[key], 1);  // LDS atomic: local rank
    }
    __syncthreads();
    const int lc = lhist[threadIdx.x];
    if (lc > 0) lbase[threadIdx.x] = atomicAdd(&kcur[threadIdx.x], lc);
    __syncthreads();
    if (valid) {
      snodes[khist[key] + lbase[key] + lrank] = t;
    }
    return;
  }
  int e = blockIdx.x * 256 + threadIdx.x;
  {
    int t = dst[e];
    int4 nf = ninfo[t];
    int pos;
    if (e < HALF) {
      pos = nf.x + atomicAdd(&cur_in[t], 1);
    } else {
      pos = nf.x + nf.z + atomicAdd(&cur_out[t], 1);
    }
    em[pos] = make_int2(src[e] | (etype[e] << 16), __float_as_int(norm[e]));
  }
}

// ---------------- fused: gather + attention + z accum + MFMA ----------------
// Round-9 config + degree-balanced node mapping: block b, wave w, slot nn
// processes sorted-rank nn*4*NTILES + w*NTILES + b — every wave and every
// block spans the degree distribution uniformly (no barrier/drain waste).
__global__ __launch_bounds__(256) void fused_kernel(
    const _Float16* __restrict__ nrp_h, const _Float16* __restrict__ rel_h,
    const int4* __restrict__ ninfo, const float* __restrict__ qbuf,
    const float* __restrict__ cbuf, const int2* __restrict__ em,
    const _Float16* __restrict__ Mh, const int* __restrict__ snodes,
    float* __restrict__ h) {
  __shared__ __align__(16) _Float16 z16[16384];  // 16 nodes x 2048B, swizzled
  const int w = threadIdx.x >> 6;
  const int lane = threadIdx.x & 63;
  const int dirg = lane >> 5;        // 0: in-edges, 1: out-edges
  const int slot = (lane >> 4) & 1;  // edge slot within dir
  const int ll = lane & 15;          // 8-channel chunk
  const int ch0 = ll * 8;

  // c_k chunks: register-resident (8 floats per k)
  float4 ckA[4], ckB[4];
#pragma unroll
  for (int k = 0; k < 4; ++k) {
    ckA[k] = *(const float4*)(cbuf + k * C + ch0);
    ckB[k] = *(const float4*)(cbuf + k * C + ch0 + 4);
  }

  // ---- phase 1: per-node edge loop, 4 edges per wave-iteration ----
  for (int nn = 0; nn < 4; ++nn) {
    const int node = w * 4 + nn;               // block-local 0..15
    const int t = snodes[nn * 4 * NTILES + w * NTILES + blockIdx.x];
    const int4 nfo = ninfo[t];
    const int start = nfo.x, deg = nfo.y, ni = nfo.z;
    const float4 q4 = *(const float4*)(qbuf + 4 * (size_t)t);
    const int sidx = dirg ? ni : 0;
    const int nmy = dirg ? (deg - ni) : ni;
    const int nmax = max(ni, deg - ni);        // wave-uniform

    float4 zA[4], zB[4];
#pragma unroll
    for (int k = 0; k < 4; ++k) {
      zA[k] = make_float4(0.f, 0.f, 0.f, 0.f);
      zB[k] = make_float4(0.f, 0.f, 0.f, 0.f);
    }

    if (nmax > 0) {
      // stage: em0 -> current (j), em1 -> next (j+2); rows for j in flight
      int2 em0 = em[start + min(sidx + slot, deg - 1)];
      int2 em1 = em[start + min(sidx + 2 + slot, deg - 1)];
      f16x8 ah = *(const f16x8*)(nrp_h + (size_t)(em0.x & 0xFFFF) * C + ch0);
      f16x8 bh = *(const f16x8*)(rel_h + (size_t)((em0.x >> 16) & 0x1FF) * C + ch0);

      for (int j = 0; j < nmax; j += 2) {
        // stage meta for j+4 (no dependencies; wave-uniform condition)
        int2 em2 = em1;
        if (j + 4 < nmax) em2 = em[start + min(sidx + j + 4 + slot, deg - 1)];
        // stage rows for j+2 using em1 (arrived a full iteration ago)
        f16x8 ahn = ah, bhn = bh;
        if (j + 2 < nmax) {
          ahn = *(const f16x8*)(nrp_h + (size_t)(em1.x & 0xFFFF) * C + ch0);
          bhn = *(const f16x8*)(rel_h + (size_t)((em1.x >> 16) & 0x1FF) * C + ch0);
        }
        // compute current edge (j + slot): x = a*b in f32
        float4 xA, xB;
        xA.x = (float)ah[0] * (float)bh[0];
        xA.y = (float)ah[1] * (float)bh[1];
        xA.z = (float)ah[2] * (float)bh[2];
        xA.w = (float)ah[3] * (float)bh[3];
        xB.x = (float)ah[4] * (float)bh[4];
        xB.y = (float)ah[5] * (float)bh[5];
        xB.z = (float)ah[6] * (float)bh[6];
        xB.w = (float)ah[7] * (float)bh[7];
        float p0 = xA.x * ckA[0].x + xA.y * ckA[0].y + xA.z * ckA[0].z + xA.w * ckA[0].w
                 + xB.x * ckB[0].x + xB.y * ckB[0].y + xB.z * ckB[0].z + xB.w * ckB[0].w;
        float p1 = xA.x * ckA[1].x + xA.y * ckA[1].y + xA.z * ckA[1].z + xA.w * ckA[1].w
                 + xB.x * ckB[1].x + xB.y * ckB[1].y + xB.z * ckB[1].z + xB.w * ckB[1].w;
        float p2 = xA.x * ckA[2].x + xA.y * ckA[2].y + xA.z * ckA[2].z + xA.w * ckA[2].w
                 + xB.x * ckB[2].x + xB.y * ckB[2].y + xB.z * ckB[2].z + xB.w * ckB[2].w;
        float p3 = xA.x * ckA[3].x + xA.y * ckA[3].y + xA.z * ckA[3].z + xA.w * ckA[3].w
                 + xB.x * ckB[3].x + xB.y * ckB[3].y + xB.z * ckB[3].z + xB.w * ckB[3].w;
#pragma unroll
        for (int m = 1; m < 16; m <<= 1) {
          p0 += __shfl_xor(p0, m);
          p1 += __shfl_xor(p1, m);
          p2 += __shfl_xor(p2, m);
          p3 += __shfl_xor(p3, m);
        }
        // softmax (no max-sub: logits are relu'd and small for this model)
        float l0 = fmaxf(p0 + q4.x, 0.f);
        float l1 = fmaxf(p1 + q4.y, 0.f);
        float l2 = fmaxf(p2 + q4.z, 0.f);
        float l3 = fmaxf(p3 + q4.w, 0.f);
        float e0f = __expf(l0), e1f = __expf(l1);
        float e2f = __expf(l2), e3f = __expf(l3);
        float nr = __int_as_float(em0.y);
        float inv = ((j + slot) < nmy) ? (nr / (e0f + e1f + e2f + e3f)) : 0.f;
        float w0 = e0f * inv, w1 = e1f * inv, w2 = e2f * inv, w3 = e3f * inv;
        zA[0].x += w0 * xA.x; zA[0].y += w0 * xA.y; zA[0].z += w0 * xA.z; zA[0].w += w0 * xA.w;
        zB[0].x += w0 * xB.x; zB[0].y += w0 * xB.y; zB[0].z += w0 * xB.z; zB[0].w += w0 * xB.w;
        zA[1].x += w1 * xA.x; zA[1].y += w1 * xA.y; zA[1].z += w1 * xA.z; zA[1].w += w1 * xA.w;
        zB[1].x += w1 * xB.x; zB[1].y += w1 * xB.y; zB[1].z += w1 * xB.z; zB[1].w += w1 * xB.w;
        zA[2].x += w2 * xA.x; zA[2].y += w2 * xA.y; zA[2].z += w2 * xA.z; zA[2].w += w2 * xA.w;
        zB[2].x += w2 * xB.x; zB[2].y += w2 * xB.y; zB[2].z += w2 * xB.z; zB[2].w += w2 * xB.w;
        zA[3].x += w3 * xA.x; zA[3].y += w3 * xA.y; zA[3].z += w3 * xA.z; zA[3].w += w3 * xA.w;
        zB[3].x += w3 * xB.x; zB[3].y += w3 * xB.y; zB[3].z += w3 * xB.z; zB[3].w += w3 * xB.w;
        // rotate pipeline
        em0 = em1; em1 = em2;
        ah = ahn; bh = bhn;
      }
    }

    // combine the two slots of each dir (lane ^ 16 stays within the dir half)
#pragma unroll
    for (int k = 0; k < 4; ++k) {
      zA[k].x += __shfl_xor(zA[k].x, 16);
      zA[k].y += __shfl_xor(zA[k].y, 16);
      zA[k].z += __shfl_xor(zA[k].z, 16);
      zA[k].w += __shfl_xor(zA[k].w, 16);
      zB[k].x += __shfl_xor(zB[k].x, 16);
      zB[k].y += __shfl_xor(zB[k].y, 16);
      zB[k].z += __shfl_xor(zB[k].z, 16);
      zB[k].w += __shfl_xor(zB[k].w, 16);
    }
    // write f16 z: byte = node*2048 + dir*1024 + k*256 + ((ll*16) ^ swz)
    if (slot == 0) {
      const int swz = (node & 7) << 4;
      char* zb = (char*)z16 + node * 2048 + dirg * 1024 + ((ll * 16) ^ swz);
#pragma unroll
      for (int k = 0; k < 4; ++k) {
        f16x8 o;
        o[0] = (_Float16)zA[k].x; o[1] = (_Float16)zA[k].y;
        o[2] = (_Float16)zA[k].z; o[3] = (_Float16)zA[k].w;
        o[4] = (_Float16)zB[k].x; o[5] = (_Float16)zB[k].y;
        o[6] = (_Float16)zB[k].z; o[7] = (_Float16)zB[k].w;
        *(f16x8*)(zb + k * 256) = o;
      }
    }
  }
  __syncthreads();

  // ---- phase 2: MFMA contraction; wave = k ----
  const int kk = w;
  const int lo16 = lane & 15;       // A row (node) / B col (o) / C col (o)
  const int kq = lane >> 4;         // k-chunk quarter
  {
    const int anode = lo16;
    const int aswz = (anode & 7) << 4;
    const char* zb = (const char*)z16 + anode * 2048 + kk * 256;
    f16x8 a[2][4];
#pragma unroll
    for (int d = 0; d < 2; ++d)
#pragma unroll
      for (int kc = 0; kc < 4; ++kc)
        a[d][kc] = *(const f16x8*)(zb + d * 1024 + ((kc * 64 + kq * 16) ^ aswz));

    f32x4 c0 = {0.f, 0.f, 0.f, 0.f};
    f32x4 c1 = {0.f, 0.f, 0.f, 0.f};
#pragma unroll
    for (int d = 0; d < 2; ++d)
#pragma unroll
      for (int kc = 0; kc < 4; ++kc) {
        const _Float16* mb = Mh + (((d * 4 + kk) * 2) * 16 + lo16) * 128 + kc * 32 + kq * 8;
        f16x8 b0 = *(const f16x8*)(mb);
        f16x8 b1 = *(const f16x8*)(mb + 2048);
        c0 = __builtin_amdgcn_mfma_f32_16x16x32_f16(a[d][kc], b0, c0, 0, 0, 0);
        c1 = __builtin_amdgcn_mfma_f32_16x16x32_f16(a[d][kc], b1, c1, 0, 0, 0);
      }

    const float third = 1.f / 3.f;
#pragma unroll
    for (int r = 0; r < 4; ++r) {
      // block-local node kq*4+r -> real id via the same mapping
      int tt = snodes[r * 4 * NTILES + kq * NTILES + blockIdx.x];
      size_t hb = (size_t)tt * C + kk * 32 + lo16;
      h[hb] = c0[r] * third;
      h[hb + 16] = c1[r] * third;
    }
  }
}

// ---------------- self-loop (MFMA) + bias + BN partial stats ----------------
// Persistent: 1280 blocks x 256 threads grid-stride over 16-row h tiles.
__global__ __launch_bounds__(256) void selfloop_kernel(
    float* __restrict__ h, const _Float16* __restrict__ LWh,
    const float* __restrict__ bias,
    float* __restrict__ bnsum, float* __restrict__ bnsq) {
  __shared__ __align__(16) _Float16 hf[2048];  // 16 rows x 256B, swizzled
  const int tid = threadIdx.x;
  const int w = tid >> 6, lane = tid & 63;
  const int row = tid >> 4;          // loader row 0..15
  const int l = tid & 15;            // loader 8-chunk
  const int lo16 = lane & 15;
  const int kq = lane >> 4;
  const float bv0 = bias[w * 32 + lo16];
  const float bv1 = bias[w * 32 + 16 + lo16];
  float s0 = 0.f, s1 = 0.f, sq0 = 0.f, sq1 = 0.f;

  const int aswz = (lo16 & 7) << 4;
  const int lswz = (row & 7) << 4;

  for (int tile = blockIdx.x; tile < NTILES; tile += gridDim.x) {
    // stage h tile as f16 (swizzled)
    {
      const float* hp = h + (size_t)(tile * 16 + row) * C + l * 8;
      float4 v0 = *(const float4*)(hp);
      float4 v1 = *(const float4*)(hp + 4);
      f16x8 o;
      o[0] = (_Float16)v0.x; o[1] = (_Float16)v0.y;
      o[2] = (_Float16)v0.z; o[3] = (_Float16)v0.w;
      o[4] = (_Float16)v1.x; o[5] = (_Float16)v1.y;
      o[6] = (_Float16)v1.z; o[7] = (_Float16)v1.w;
      *(f16x8*)((char*)hf + row * 256 + ((l * 16) ^ lswz)) = o;
    }
    __syncthreads();

    // MFMA: wave w -> output otiles 2w, 2w+1
    const char* zb = (const char*)hf + lo16 * 256;
    f32x4 c0 = {0.f, 0.f, 0.f, 0.f};
    f32x4 c1 = {0.f, 0.f, 0.f, 0.f};
#pragma unroll
    for (int kc = 0; kc < 4; ++kc) {
      f16x8 a = *(const f16x8*)(zb + ((kc * 64 + kq * 16) ^ aswz));
      const _Float16* mb = LWh + ((w * 2) * 16 + lo16) * 128 + kc * 32 + kq * 8;
      f16x8 b0 = *(const f16x8*)(mb);
      f16x8 b1 = *(const f16x8*)(mb + 2048);
      c0 = __builtin_amdgcn_mfma_f32_16x16x32_f16(a, b0, c0, 0, 0, 0);
      c1 = __builtin_amdgcn_mfma_f32_16x16x32_f16(a, b1, c1, 0, 0, 0);
    }

    // epilogue: h_new = h_orig(f32) + c + bias; BN stats
#pragma unroll
    for (int r = 0; r < 4; ++r) {
      int tt = tile * 16 + kq * 4 + r;
      size_t hb = (size_t)tt * C + w * 32 + lo16;
      float h0 = h[hb] + c0[r] + bv0;
      float h1 = h[hb + 16] + c1[r] + bv1;
      h[hb] = h0;
      h[hb + 16] = h1;
      s0 += h0; s1 += h1; sq0 += h0 * h0; sq1 += h1 * h1;
    }
    __syncthreads();  // done reading hf before next tile's writes
  }

  // reduce over kq (lanes lo16, +16, +32, +48), one atomic batch per column
  s0 += __shfl_xor(s0, 16); s0 += __shfl_xor(s0, 32);
  s1 += __shfl_xor(s1, 16); s1 += __shfl_xor(s1, 32);
  sq0 += __shfl_xor(sq0, 16); sq0 += __shfl_xor(sq0, 32);
  sq1 += __shfl_xor(sq1, 16); sq1 += __shfl_xor(sq1, 32);
  if (kq == 0) {
    atomicAdd(&bnsum[w * 32 + lo16], s0);
    atomicAdd(&bnsum[w * 32 + 16 + lo16], s1);
    atomicAdd(&bnsq[w * 32 + lo16], sq0);
    atomicAdd(&bnsq[w * 32 + 16 + lo16], sq1);
  }
}

// ---------------- BN finalize + tanh (fused) --------------------------------
__global__ void tanh_kernel(float* __restrict__ h,
                            const float* __restrict__ bnsum, const float* __restrict__ bnsq,
                            const float* __restrict__ gamma, const float* __restrict__ beta) {
  int idx = blockIdx.x * 256 + threadIdx.x;
  int base = idx * 4;
  if (base >= V * C) return;
  int j = base & 127;
  const float invV = 1.f / (float)V;
  float4 v = *(float4*)(h + base);
  float o[4] = {v.x, v.y, v.z, v.w};
#pragma unroll
  for (int cidx = 0; cidx < 4; ++cidx) {
    float mean = bnsum[j + cidx] * invV;
    float var = bnsq[j + cidx] * invV - mean * mean;
    float sc = gamma[j + cidx] * rsqrtf(var + 1e-5f);
    float sh = beta[j + cidx] - sc * mean;
    o[cidx] = tanhf(sc * o[cidx] + sh);
  }
  v.x = o[0]; v.y = o[1]; v.z = o[2]; v.w = o[3];
  *(float4*)(h + base) = v;
}

extern "C" void kernel_launch(void* const* d_in, const int* in_sizes, int n_in,
                              void* d_out, int out_size, void* d_ws, size_t ws_size,
                              hipStream_t stream) {
  const float* node_repr  = (const float*)d_in[0];
  const float* rel_repr   = (const float*)d_in[1];
  const int*   src        = (const int*)d_in[2];
  const int*   dst        = (const int*)d_in[3];
  const int*   etype      = (const int*)d_in[4];
  const float* norm       = (const float*)d_in[5];
  const float* node_w     = (const float*)d_in[6];
  const float* node_rel_w = (const float*)d_in[7];
  const float* in_w       = (const float*)d_in[8];
  const float* out_w      = (const float*)d_in[9];
  const float* att_w      = (const float*)d_in[10];
  const float* loop_rel   = (const float*)d_in[11];
  const float* loop_w     = (const float*)d_in[12];
  const float* w_rel      = (const float*)d_in[13];
  const float* bias       = (const float*)d_in[14];
  const float* bn_gamma   = (const float*)d_in[15];
  const float* bn_beta    = (const float*)d_in[16];

  float* out = (float*)d_out;
  float* h = out;                       // [V,128] accumulator, finalized in place
  float* rel_out = out + (size_t)V * C; // [474,128]

  // workspace layout (16B alignment maintained for int4/float4 users)
  int* cnt = (int*)d_ws;                // V
  int* cur_in = cnt + V;                // V
  int* cin = cur_in + V;                // V
  int* cur_out = cin + V;               // V
  float* bnsum = (float*)(cur_out + V); // 128
  float* bnsq = bnsum + 128;            // 128
  int* khist = (int*)(bnsq + 128);      // 256
  int* kcur = khist + 256;              // 256  -- zero region ends (4V+768)
  int* bsum = kcur + 256;               // 256
  int* snodes = bsum + 256;             // V
  int4* ninfo = (int4*)(snodes + V);    // V int4 (offset 5V+1280 ints, 16B ok)
  int2* em = (int2*)(ninfo + V);        // E int2
  float* qbuf = (float*)(em + E);       // 4V
  float* cbuf = qbuf + 4 * V;           // 512
  float* bbuf = cbuf + 512;             // 512
  _Float16* Mh = (_Float16*)(bbuf + 512);   // 32768 halves (f16 B-frag layout)
  _Float16* LWh = Mh + 32768;           // 16384 halves (selfloop B-frag)
  _Float16* nrp_h = LWh + 16384;        // V*C halves (12.8 MB)
  _Float16* rel_h = nrp_h + (size_t)V * C; // 474*128 halves

  hipMemsetAsync(cnt, 0, (size_t)(4 * V + 768) * 4, stream);

  prep_kernel<<<(1024 + 32768 + NREL2 * C / 8 + 16384 + 255) / 256, 256, 0, stream>>>(
      node_rel_w, node_w, in_w, out_w, att_w, rel_repr, loop_rel, loop_w,
      cbuf, bbuf, Mh, rel_h, LWh);
  qnode_kernel<<<NQBLK + RELBLK + HISTBLK, 256, 0, stream>>>(
      node_repr, bbuf, qbuf, nrp_h, rel_repr, w_rel, rel_out, dst, cnt, cin);
  scan_sum_kernel<<<NCHUNK, 256, 0, stream>>>(cnt, bsum);
  scan_apply_kernel<<<NCHUNK, 256, 0, stream>>>(cnt, cin, bsum, ninfo, khist);
  keyscan_kernel<<<1, 256, 0, stream>>>(khist);
  place_kernel<<<E / 256 + NCHUNK, 256, 0, stream>>>(dst, src, etype, norm, ninfo,
                                                     cur_in, cur_out, em,
                                                     khist, kcur, snodes);
  fused_kernel<<<NTILES, 256, 0, stream>>>(nrp_h, rel_h, ninfo, qbuf, cbuf, em,
                                           Mh, snodes, h);
  selfloop_kernel<<<1280, 256, 0, stream>>>(h, LWh, bias, bnsum, bnsq);
  tanh_kernel<<<(V * C / 4 + 255) / 256, 256, 0, stream>>>(h, bnsum, bnsq, bn_gamma, bn_beta);
}

// Round 19
// 279.919 us; speedup vs baseline: 2.3628x; 1.0421x over previous
//
#include <hip/hip_runtime.h>

namespace {
constexpr int V = 50000;
constexpr int E = 640000;
constexpr int HALF = 320000;
constexpr int NREL2 = 474;
constexpr int C = 128;
constexpr int NCHUNK = (V + 255) / 256; // 196
constexpr int NQBLK = V / 16;           // 3125 node-blocks in qnode
constexpr int RELBLK = (NREL2 + 1) / 2; // 237 relout blocks folded into qnode
constexpr int HISTBLK = E / 256;        // 2500 hist blocks folded into qnode
constexpr int NTILES = V / 16;          // 3125
}

typedef _Float16 h4 __attribute__((ext_vector_type(4)));
typedef _Float16 f16x8 __attribute__((ext_vector_type(8)));
typedef float f32x4 __attribute__((ext_vector_type(4)));

// ---- precompute: c[k,i], b[k,i], Mh + LWh (f16 frag layouts), rel_h cast ---
// Mh[u], u = (((d*4+k)*2+ot)*16+o16)*128 + i  (d: 0=in 1=out, o = ot*16+o16)
// LWh[u], u = (ot*16+o16)*128 + i ; value = lr[i]*lw[i][o]/3
__global__ void prep_kernel(const float* __restrict__ nrw, const float* __restrict__ nw,
                            const float* __restrict__ inw, const float* __restrict__ outw,
                            const float* __restrict__ aw, const float* __restrict__ rel,
                            const float* __restrict__ lr, const float* __restrict__ lw,
                            float* __restrict__ cbuf, float* __restrict__ bbuf,
                            _Float16* __restrict__ Mh, _Float16* __restrict__ rel_h,
                            _Float16* __restrict__ LWh) {
  int tid = blockIdx.x * 256 + threadIdx.x;
  if (tid < 512) {
    int k = tid >> 7, i = tid & 127;
    float acc = 0.f;
    for (int d = 0; d < 32; ++d) acc += nrw[k*4096 + i*32 + d] * aw[d];
    cbuf[tid] = acc;
  } else if (tid < 1024) {
    int u = tid - 512; int k = u >> 7, i = u & 127;
    float acc = 0.f;
    for (int d = 0; d < 32; ++d) acc += nw[k*4096 + i*32 + d] * aw[32 + d];
    bbuf[u] = acc;
  } else if (tid < 1024 + 16384) {
    int u = tid - 1024; int k = u >> 12, rem = u & 4095, i = rem >> 5, o = rem & 31;
    float acc = 0.f;
    for (int d = 0; d < 32; ++d) acc += nrw[k*4096 + i*32 + d] * inw[k*1024 + d*32 + o];
    Mh[(((k) * 2 + (o >> 4)) * 16 + (o & 15)) * 128 + i] = (_Float16)acc;
  } else if (tid < 1024 + 32768) {
    int u = tid - 1024 - 16384; int k = u >> 12, rem = u & 4095, i = rem >> 5, o = rem & 31;
    float acc = 0.f;
    for (int d = 0; d < 32; ++d) acc += nrw[k*4096 + i*32 + d] * outw[k*1024 + d*32 + o];
    Mh[(((4 + k) * 2 + (o >> 4)) * 16 + (o & 15)) * 128 + i] = (_Float16)acc;
  } else if (tid < 1024 + 32768 + NREL2 * C / 8) {
    int u = tid - 1024 - 32768;  // 8-elem chunk of rel table
    const float4 v0 = *(const float4*)(rel + (size_t)u * 8);
    const float4 v1 = *(const float4*)(rel + (size_t)u * 8 + 4);
    f16x8 o;
    o[0] = (_Float16)v0.x; o[1] = (_Float16)v0.y;
    o[2] = (_Float16)v0.z; o[3] = (_Float16)v0.w;
    o[4] = (_Float16)v1.x; o[5] = (_Float16)v1.y;
    o[6] = (_Float16)v1.z; o[7] = (_Float16)v1.w;
    *(f16x8*)(rel_h + (size_t)u * 8) = o;
  } else if (tid < 1024 + 32768 + NREL2 * C / 8 + 16384) {
    int u = tid - 1024 - 32768 - NREL2 * C / 8;  // [o(128)][i(128)]
    int o = u >> 7, i = u & 127;
    float v = lr[i] * lw[i * C + o] * (1.f / 3.f);
    LWh[u] = (_Float16)v;
  }
}

// ---- q[t,k] = node_repr[t].b_k (16 lanes/node) + f16 node cast.
// Blocks [NQBLK, NQBLK+RELBLK): rel_out = rel @ w_rel (2 rows/block).
// Blocks [NQBLK+RELBLK, ...): edge histogram (cnt/cin atomics). -------------
__global__ __launch_bounds__(256) void qnode_kernel(const float* __restrict__ nrp,
                                                    const float* __restrict__ bbuf,
                                                    float* __restrict__ qbuf,
                                                    _Float16* __restrict__ nrp_h,
                                                    const float* __restrict__ rel,
                                                    const float* __restrict__ wrel,
                                                    float* __restrict__ rel_out,
                                                    const int* __restrict__ dst,
                                                    int* __restrict__ cnt,
                                                    int* __restrict__ cin) {
  if (blockIdx.x >= NQBLK + RELBLK) {  // folded histogram
    int e = (blockIdx.x - NQBLK - RELBLK) * 256 + threadIdx.x;
    if (e < E) {
      int t = dst[e];
      atomicAdd(&cnt[t], 1);
      if (e < HALF) atomicAdd(&cin[t], 1);
    }
    return;
  }
  if (blockIdx.x >= NQBLK) {  // folded relout (block-uniform branch)
    __shared__ float rr2[2][128];
    const int bb = blockIdx.x - NQBLK;
    const int half = threadIdx.x >> 7;
    const int t128 = threadIdx.x & 127;
    const int row = bb * 2 + half;
    if (row < NREL2) rr2[half][t128] = rel[row * C + t128];
    __syncthreads();
    if (row < NREL2) {
      float acc = 0.f;
#pragma unroll 4
      for (int i = 0; i < C; ++i) acc += rr2[half][i] * wrel[i * C + t128];
      rel_out[row * C + t128] = acc;
    }
    return;
  }
  const int t = blockIdx.x * 16 + (threadIdx.x >> 4);
  const int l = threadIdx.x & 15;
  if (t >= V) return;
  const float* row = nrp + (size_t)t * C + l * 8;
  float4 a0 = *(const float4*)(row);
  float4 a1 = *(const float4*)(row + 4);
  {
    f16x8 o;
    o[0] = (_Float16)a0.x; o[1] = (_Float16)a0.y;
    o[2] = (_Float16)a0.z; o[3] = (_Float16)a0.w;
    o[4] = (_Float16)a1.x; o[5] = (_Float16)a1.y;
    o[6] = (_Float16)a1.z; o[7] = (_Float16)a1.w;
    *(f16x8*)(nrp_h + (size_t)t * C + l * 8) = o;
  }
  float p[4];
#pragma unroll
  for (int k = 0; k < 4; ++k) {
    const float* brow = bbuf + k * C + l * 8;
    float4 b0 = *(const float4*)(brow);
    float4 b1 = *(const float4*)(brow + 4);
    p[k] = a0.x * b0.x + a0.y * b0.y + a0.z * b0.z + a0.w * b0.w
         + a1.x * b1.x + a1.y * b1.y + a1.z * b1.z + a1.w * b1.w;
  }
#pragma unroll
  for (int m = 1; m < 16; m <<= 1) {
#pragma unroll
    for (int k = 0; k < 4; ++k) p[k] += __shfl_xor(p[k], m);
  }
  if (l == 0) *(float4*)(qbuf + 4 * (size_t)t) = make_float4(p[0], p[1], p[2], p[3]);
}

// ---------------- CSR scan ---------------------------------------------------
__global__ void scan_sum_kernel(const int* __restrict__ cnt, int* __restrict__ bsum) {
  __shared__ int sd[256];
  int tid = threadIdx.x;
  int idx = blockIdx.x * 256 + tid;
  int v = (idx < V) ? cnt[idx] : 0;
  sd[tid] = v; __syncthreads();
  for (int s = 128; s > 0; s >>= 1) {
    if (tid < s) sd[tid] += sd[tid + s];
    __syncthreads();
  }
  if (tid == 0) bsum[blockIdx.x] = sd[0];
}

// per-block scan + redundant top-scan of the 196 block sums (folds scan_top);
// writes ninfo[t] = {off, deg, nin, 0}
__global__ void scan_apply_kernel(const int* __restrict__ cnt, const int* __restrict__ cin,
                                  const int* __restrict__ bsum, int4* __restrict__ ninfo) {
  __shared__ int sd[256];
  __shared__ int sb[256];
  int tid = threadIdx.x;
  int idx = blockIdx.x * 256 + tid;
  // top-scan (inclusive) of block sums — redundant per block, cheap
  int b = (tid < NCHUNK) ? bsum[tid] : 0;
  sb[tid] = b; __syncthreads();
  for (int ofs = 1; ofs < 256; ofs <<= 1) {
    int t2 = (tid >= ofs) ? sb[tid - ofs] : 0;
    __syncthreads();
    sb[tid] += t2;
    __syncthreads();
  }
  const int blockoff = (blockIdx.x == 0) ? 0 : sb[blockIdx.x - 1];
  // per-node scan
  int v = (idx < V) ? cnt[idx] : 0;
  sd[tid] = v; __syncthreads();
  for (int ofs = 1; ofs < 256; ofs <<= 1) {
    int t2 = (tid >= ofs) ? sd[tid - ofs] : 0;
    __syncthreads();
    sd[tid] += t2;
    __syncthreads();
  }
  if (idx < V) {
    ninfo[idx] = make_int4(blockoff + sd[tid] - v, v, cin[idx], 0);
  }
}

// place edges: in-edges (e < HALF) packed at off[t], out-edges after cin[t];
// em = {src|etype<<16, norm bits} single 8B store per edge.
__global__ void place_kernel(const int* __restrict__ dst, const int* __restrict__ src,
                             const int* __restrict__ etype, const float* __restrict__ norm,
                             const int4* __restrict__ ninfo,
                             int* __restrict__ cur_in, int* __restrict__ cur_out,
                             int2* __restrict__ em) {
  int e = blockIdx.x * 256 + threadIdx.x;
  if (e < E) {
    int t = dst[e];
    int4 nf = ninfo[t];
    int pos;
    if (e < HALF) {
      pos = nf.x + atomicAdd(&cur_in[t], 1);
    } else {
      pos = nf.x + nf.z + atomicAdd(&cur_out[t], 1);
    }
    em[pos] = make_int2(src[e] | (etype[e] << 16), __float_as_int(norm[e]));
  }
}

// ---------------- fused: gather + attention + z accum + MFMA ----------------
// Round-9 config (best measured): 256 threads, 4 waves, 16 nodes/block.
__global__ __launch_bounds__(256) void fused_kernel(
    const _Float16* __restrict__ nrp_h, const _Float16* __restrict__ rel_h,
    const int4* __restrict__ ninfo, const float* __restrict__ qbuf,
    const float* __restrict__ cbuf, const int2* __restrict__ em,
    const _Float16* __restrict__ Mh, float* __restrict__ h) {
  __shared__ __align__(16) _Float16 z16[16384];  // 16 nodes x 2048B, swizzled
  const int w = threadIdx.x >> 6;
  const int lane = threadIdx.x & 63;
  const int dirg = lane >> 5;        // 0: in-edges, 1: out-edges
  const int slot = (lane >> 4) & 1;  // edge slot within dir
  const int ll = lane & 15;          // 8-channel chunk
  const int ch0 = ll * 8;

  // c_k chunks: register-resident (8 floats per k)
  float4 ckA[4], ckB[4];
#pragma unroll
  for (int k = 0; k < 4; ++k) {
    ckA[k] = *(const float4*)(cbuf + k * C + ch0);
    ckB[k] = *(const float4*)(cbuf + k * C + ch0 + 4);
  }

  // ---- phase 1: per-node edge loop, 4 edges per wave-iteration ----
  for (int nn = 0; nn < 4; ++nn) {
    const int node = w * 4 + nn;               // 0..15
    const int t = blockIdx.x * 16 + node;
    const int4 nfo = ninfo[t];
    const int start = nfo.x, deg = nfo.y, ni = nfo.z;
    const float4 q4 = *(const float4*)(qbuf + 4 * (size_t)t);
    const int sidx = dirg ? ni : 0;
    const int nmy = dirg ? (deg - ni) : ni;
    const int nmax = max(ni, deg - ni);        // wave-uniform

    float4 zA[4], zB[4];
#pragma unroll
    for (int k = 0; k < 4; ++k) {
      zA[k] = make_float4(0.f, 0.f, 0.f, 0.f);
      zB[k] = make_float4(0.f, 0.f, 0.f, 0.f);
    }

    if (nmax > 0) {
      // stage: em0 -> current (j), em1 -> next (j+2); rows for j in flight
      int2 em0 = em[start + min(sidx + slot, deg - 1)];
      int2 em1 = em[start + min(sidx + 2 + slot, deg - 1)];
      f16x8 ah = *(const f16x8*)(nrp_h + (size_t)(em0.x & 0xFFFF) * C + ch0);
      f16x8 bh = *(const f16x8*)(rel_h + (size_t)((em0.x >> 16) & 0x1FF) * C + ch0);

      for (int j = 0; j < nmax; j += 2) {
        // stage meta for j+4 (no dependencies; wave-uniform condition)
        int2 em2 = em1;
        if (j + 4 < nmax) em2 = em[start + min(sidx + j + 4 + slot, deg - 1)];
        // stage rows for j+2 using em1 (arrived a full iteration ago)
        f16x8 ahn = ah, bhn = bh;
        if (j + 2 < nmax) {
          ahn = *(const f16x8*)(nrp_h + (size_t)(em1.x & 0xFFFF) * C + ch0);
          bhn = *(const f16x8*)(rel_h + (size_t)((em1.x >> 16) & 0x1FF) * C + ch0);
        }
        // compute current edge (j + slot): x = a*b in f32
        float4 xA, xB;
        xA.x = (float)ah[0] * (float)bh[0];
        xA.y = (float)ah[1] * (float)bh[1];
        xA.z = (float)ah[2] * (float)bh[2];
        xA.w = (float)ah[3] * (float)bh[3];
        xB.x = (float)ah[4] * (float)bh[4];
        xB.y = (float)ah[5] * (float)bh[5];
        xB.z = (float)ah[6] * (float)bh[6];
        xB.w = (float)ah[7] * (float)bh[7];
        float p0 = xA.x * ckA[0].x + xA.y * ckA[0].y + xA.z * ckA[0].z + xA.w * ckA[0].w
                 + xB.x * ckB[0].x + xB.y * ckB[0].y + xB.z * ckB[0].z + xB.w * ckB[0].w;
        float p1 = xA.x * ckA[1].x + xA.y * ckA[1].y + xA.z * ckA[1].z + xA.w * ckA[1].w
                 + xB.x * ckB[1].x + xB.y * ckB[1].y + xB.z * ckB[1].z + xB.w * ckB[1].w;
        float p2 = xA.x * ckA[2].x + xA.y * ckA[2].y + xA.z * ckA[2].z + xA.w * ckA[2].w
                 + xB.x * ckB[2].x + xB.y * ckB[2].y + xB.z * ckB[2].z + xB.w * ckB[2].w;
        float p3 = xA.x * ckA[3].x + xA.y * ckA[3].y + xA.z * ckA[3].z + xA.w * ckA[3].w
                 + xB.x * ckB[3].x + xB.y * ckB[3].y + xB.z * ckB[3].z + xB.w * ckB[3].w;
#pragma unroll
        for (int m = 1; m < 16; m <<= 1) {
          p0 += __shfl_xor(p0, m);
          p1 += __shfl_xor(p1, m);
          p2 += __shfl_xor(p2, m);
          p3 += __shfl_xor(p3, m);
        }
        // softmax (no max-sub: logits are relu'd and small for this model)
        float l0 = fmaxf(p0 + q4.x, 0.f);
        float l1 = fmaxf(p1 + q4.y, 0.f);
        float l2 = fmaxf(p2 + q4.z, 0.f);
        float l3 = fmaxf(p3 + q4.w, 0.f);
        float e0f = __expf(l0), e1f = __expf(l1);
        float e2f = __expf(l2), e3f = __expf(l3);
        float nr = __int_as_float(em0.y);
        float inv = ((j + slot) < nmy) ? (nr / (e0f + e1f + e2f + e3f)) : 0.f;
        float w0 = e0f * inv, w1 = e1f * inv, w2 = e2f * inv, w3 = e3f * inv;
        zA[0].x += w0 * xA.x; zA[0].y += w0 * xA.y; zA[0].z += w0 * xA.z; zA[0].w += w0 * xA.w;
        zB[0].x += w0 * xB.x; zB[0].y += w0 * xB.y; zB[0].z += w0 * xB.z; zB[0].w += w0 * xB.w;
        zA[1].x += w1 * xA.x; zA[1].y += w1 * xA.y; zA[1].z += w1 * xA.z; zA[1].w += w1 * xA.w;
        zB[1].x += w1 * xB.x; zB[1].y += w1 * xB.y; zB[1].z += w1 * xB.z; zB[1].w += w1 * xB.w;
        zA[2].x += w2 * xA.x; zA[2].y += w2 * xA.y; zA[2].z += w2 * xA.z; zA[2].w += w2 * xA.w;
        zB[2].x += w2 * xB.x; zB[2].y += w2 * xB.y; zB[2].z += w2 * xB.z; zB[2].w += w2 * xB.w;
        zA[3].x += w3 * xA.x; zA[3].y += w3 * xA.y; zA[3].z += w3 * xA.z; zA[3].w += w3 * xA.w;
        zB[3].x += w3 * xB.x; zB[3].y += w3 * xB.y; zB[3].z += w3 * xB.z; zB[3].w += w3 * xB.w;
        // rotate pipeline
        em0 = em1; em1 = em2;
        ah = ahn; bh = bhn;
      }
    }

    // combine the two slots of each dir (lane ^ 16 stays within the dir half)
#pragma unroll
    for (int k = 0; k < 4; ++k) {
      zA[k].x += __shfl_xor(zA[k].x, 16);
      zA[k].y += __shfl_xor(zA[k].y, 16);
      zA[k].z += __shfl_xor(zA[k].z, 16);
      zA[k].w += __shfl_xor(zA[k].w, 16);
      zB[k].x += __shfl_xor(zB[k].x, 16);
      zB[k].y += __shfl_xor(zB[k].y, 16);
      zB[k].z += __shfl_xor(zB[k].z, 16);
      zB[k].w += __shfl_xor(zB[k].w, 16);
    }
    // write f16 z: byte = node*2048 + dir*1024 + k*256 + ((ll*16) ^ swz)
    if (slot == 0) {
      const int swz = (node & 7) << 4;
      char* zb = (char*)z16 + node * 2048 + dirg * 1024 + ((ll * 16) ^ swz);
#pragma unroll
      for (int k = 0; k < 4; ++k) {
        f16x8 o;
        o[0] = (_Float16)zA[k].x; o[1] = (_Float16)zA[k].y;
        o[2] = (_Float16)zA[k].z; o[3] = (_Float16)zA[k].w;
        o[4] = (_Float16)zB[k].x; o[5] = (_Float16)zB[k].y;
        o[6] = (_Float16)zB[k].z; o[7] = (_Float16)zB[k].w;
        *(f16x8*)(zb + k * 256) = o;
      }
    }
  }
  __syncthreads();

  // ---- phase 2: MFMA contraction; wave = k ----
  const int kk = w;
  const int lo16 = lane & 15;       // A row (node) / B col (o) / C col (o)
  const int kq = lane >> 4;         // k-chunk quarter
  {
    const int anode = lo16;
    const int aswz = (anode & 7) << 4;
    const char* zb = (const char*)z16 + anode * 2048 + kk * 256;
    f16x8 a[2][4];
#pragma unroll
    for (int d = 0; d < 2; ++d)
#pragma unroll
      for (int kc = 0; kc < 4; ++kc)
        a[d][kc] = *(const f16x8*)(zb + d * 1024 + ((kc * 64 + kq * 16) ^ aswz));

    f32x4 c0 = {0.f, 0.f, 0.f, 0.f};
    f32x4 c1 = {0.f, 0.f, 0.f, 0.f};
#pragma unroll
    for (int d = 0; d < 2; ++d)
#pragma unroll
      for (int kc = 0; kc < 4; ++kc) {
        const _Float16* mb = Mh + (((d * 4 + kk) * 2) * 16 + lo16) * 128 + kc * 32 + kq * 8;
        f16x8 b0 = *(const f16x8*)(mb);
        f16x8 b1 = *(const f16x8*)(mb + 2048);
        c0 = __builtin_amdgcn_mfma_f32_16x16x32_f16(a[d][kc], b0, c0, 0, 0, 0);
        c1 = __builtin_amdgcn_mfma_f32_16x16x32_f16(a[d][kc], b1, c1, 0, 0, 0);
      }

    const float third = 1.f / 3.f;
#pragma unroll
    for (int r = 0; r < 4; ++r) {
      int tt = blockIdx.x * 16 + kq * 4 + r;
      if (tt < V) {
        size_t hb = (size_t)tt * C + kk * 32 + lo16;
        h[hb] = c0[r] * third;
        h[hb + 16] = c1[r] * third;
      }
    }
  }
}

// ---------------- self-loop (MFMA) + bias + BN partial stats ----------------
// Persistent: 1280 blocks x 256 threads grid-stride over 16-row h tiles.
__global__ __launch_bounds__(256) void selfloop_kernel(
    float* __restrict__ h, const _Float16* __restrict__ LWh,
    const float* __restrict__ bias,
    float* __restrict__ bnsum, float* __restrict__ bnsq) {
  __shared__ __align__(16) _Float16 hf[2048];  // 16 rows x 256B, swizzled
  const int tid = threadIdx.x;
  const int w = tid >> 6, lane = tid & 63;
  const int row = tid >> 4;          // loader row 0..15
  const int l = tid & 15;            // loader 8-chunk
  const int lo16 = lane & 15;
  const int kq = lane >> 4;
  const float bv0 = bias[w * 32 + lo16];
  const float bv1 = bias[w * 32 + 16 + lo16];
  float s0 = 0.f, s1 = 0.f, sq0 = 0.f, sq1 = 0.f;

  const int aswz = (lo16 & 7) << 4;
  const int lswz = (row & 7) << 4;

  for (int tile = blockIdx.x; tile < NTILES; tile += gridDim.x) {
    // stage h tile as f16 (swizzled)
    {
      const float* hp = h + (size_t)(tile * 16 + row) * C + l * 8;
      float4 v0 = *(const float4*)(hp);
      float4 v1 = *(const float4*)(hp + 4);
      f16x8 o;
      o[0] = (_Float16)v0.x; o[1] = (_Float16)v0.y;
      o[2] = (_Float16)v0.z; o[3] = (_Float16)v0.w;
      o[4] = (_Float16)v1.x; o[5] = (_Float16)v1.y;
      o[6] = (_Float16)v1.z; o[7] = (_Float16)v1.w;
      *(f16x8*)((char*)hf + row * 256 + ((l * 16) ^ lswz)) = o;
    }
    __syncthreads();

    // MFMA: wave w -> output otiles 2w, 2w+1
    const char* zb = (const char*)hf + lo16 * 256;
    f32x4 c0 = {0.f, 0.f, 0.f, 0.f};
    f32x4 c1 = {0.f, 0.f, 0.f, 0.f};
#pragma unroll
    for (int kc = 0; kc < 4; ++kc) {
      f16x8 a = *(const f16x8*)(zb + ((kc * 64 + kq * 16) ^ aswz));
      const _Float16* mb = LWh + ((w * 2) * 16 + lo16) * 128 + kc * 32 + kq * 8;
      f16x8 b0 = *(const f16x8*)(mb);
      f16x8 b1 = *(const f16x8*)(mb + 2048);
      c0 = __builtin_amdgcn_mfma_f32_16x16x32_f16(a, b0, c0, 0, 0, 0);
      c1 = __builtin_amdgcn_mfma_f32_16x16x32_f16(a, b1, c1, 0, 0, 0);
    }

    // epilogue: h_new = h_orig(f32) + c + bias; BN stats
#pragma unroll
    for (int r = 0; r < 4; ++r) {
      int tt = tile * 16 + kq * 4 + r;
      size_t hb = (size_t)tt * C + w * 32 + lo16;
      float h0 = h[hb] + c0[r] + bv0;
      float h1 = h[hb + 16] + c1[r] + bv1;
      h[hb] = h0;
      h[hb + 16] = h1;
      s0 += h0; s1 += h1; sq0 += h0 * h0; sq1 += h1 * h1;
    }
    __syncthreads();  // done reading hf before next tile's writes
  }

  // reduce over kq (lanes lo16, +16, +32, +48), one atomic batch per column
  s0 += __shfl_xor(s0, 16); s0 += __shfl_xor(s0, 32);
  s1 += __shfl_xor(s1, 16); s1 += __shfl_xor(s1, 32);
  sq0 += __shfl_xor(sq0, 16); sq0 += __shfl_xor(sq0, 32);
  sq1 += __shfl_xor(sq1, 16); sq1 += __shfl_xor(sq1, 32);
  if (kq == 0) {
    atomicAdd(&bnsum[w * 32 + lo16], s0);
    atomicAdd(&bnsum[w * 32 + 16 + lo16], s1);
    atomicAdd(&bnsq[w * 32 + lo16], sq0);
    atomicAdd(&bnsq[w * 32 + 16 + lo16], sq1);
  }
}

// ---------------- BN finalize + tanh (fused) --------------------------------
__global__ void tanh_kernel(float* __restrict__ h,
                            const float* __restrict__ bnsum, const float* __restrict__ bnsq,
                            const float* __restrict__ gamma, const float* __restrict__ beta) {
  int idx = blockIdx.x * 256 + threadIdx.x;
  int base = idx * 4;
  if (base >= V * C) return;
  int j = base & 127;
  const float invV = 1.f / (float)V;
  float4 v = *(float4*)(h + base);
  float o[4] = {v.x, v.y, v.z, v.w};
#pragma unroll
  for (int cidx = 0; cidx < 4; ++cidx) {
    float mean = bnsum[j + cidx] * invV;
    float var = bnsq[j + cidx] * invV - mean * mean;
    float sc = gamma[j + cidx] * rsqrtf(var + 1e-5f);
    float sh = beta[j + cidx] - sc * mean;
    o[cidx] = tanhf(sc * o[cidx] + sh);
  }
  v.x = o[0]; v.y = o[1]; v.z = o[2]; v.w = o[3];
  *(float4*)(h + base) = v;
}

extern "C" void kernel_launch(void* const* d_in, const int* in_sizes, int n_in,
                              void* d_out, int out_size, void* d_ws, size_t ws_size,
                              hipStream_t stream) {
  const float* node_repr  = (const float*)d_in[0];
  const float* rel_repr   = (const float*)d_in[1];
  const int*   src        = (const int*)d_in[2];
  const int*   dst        = (const int*)d_in[3];
  const int*   etype      = (const int*)d_in[4];
  const float* norm       = (const float*)d_in[5];
  const float* node_w     = (const float*)d_in[6];
  const float* node_rel_w = (const float*)d_in[7];
  const float* in_w       = (const float*)d_in[8];
  const float* out_w      = (const float*)d_in[9];
  const float* att_w      = (const float*)d_in[10];
  const float* loop_rel   = (const float*)d_in[11];
  const float* loop_w     = (const float*)d_in[12];
  const float* w_rel      = (const float*)d_in[13];
  const float* bias       = (const float*)d_in[14];
  const float* bn_gamma   = (const float*)d_in[15];
  const float* bn_beta    = (const float*)d_in[16];

  float* out = (float*)d_out;
  float* h = out;                       // [V,128] accumulator, finalized in place
  float* rel_out = out + (size_t)V * C; // [474,128]

  // workspace layout (16B alignment maintained for int4/float4 users)
  int* cnt = (int*)d_ws;                // V
  int* cur_in = cnt + V;                // V
  int* cin = cur_in + V;                // V
  int* cur_out = cin + V;               // V
  float* bnsum = (float*)(cur_out + V); // 128
  float* bnsq = bnsum + 128;            // 128  -- zero region ends (4V+256)
  int* bsum = (int*)(bnsq + 128);       // 256
  int4* ninfo = (int4*)(bsum + 256);    // V int4 (16B aligned: 4V+512 ints)
  int2* em = (int2*)(ninfo + V);        // E int2
  float* qbuf = (float*)(em + E);       // 4V
  float* cbuf = qbuf + 4 * V;           // 512
  float* bbuf = cbuf + 512;             // 512
  _Float16* Mh = (_Float16*)(bbuf + 512);   // 32768 halves (f16 B-frag layout)
  _Float16* LWh = Mh + 32768;           // 16384 halves (selfloop B-frag)
  _Float16* nrp_h = LWh + 16384;        // V*C halves (12.8 MB)
  _Float16* rel_h = nrp_h + (size_t)V * C; // 474*128 halves

  hipMemsetAsync(cnt, 0, (size_t)(4 * V + 256) * 4, stream);

  prep_kernel<<<(1024 + 32768 + NREL2 * C / 8 + 16384 + 255) / 256, 256, 0, stream>>>(
      node_rel_w, node_w, in_w, out_w, att_w, rel_repr, loop_rel, loop_w,
      cbuf, bbuf, Mh, rel_h, LWh);
  qnode_kernel<<<NQBLK + RELBLK + HISTBLK, 256, 0, stream>>>(
      node_repr, bbuf, qbuf, nrp_h, rel_repr, w_rel, rel_out, dst, cnt, cin);
  scan_sum_kernel<<<NCHUNK, 256, 0, stream>>>(cnt, bsum);
  scan_apply_kernel<<<NCHUNK, 256, 0, stream>>>(cnt, cin, bsum, ninfo);
  place_kernel<<<E / 256, 256, 0, stream>>>(dst, src, etype, norm, ninfo,
                                            cur_in, cur_out, em);
  fused_kernel<<<(V + 15) / 16, 256, 0, stream>>>(nrp_h, rel_h, ninfo,
                                                  qbuf, cbuf, em, Mh, h);
  selfloop_kernel<<<1280, 256, 0, stream>>>(h, LWh, bias, bnsum, bnsq);
  tanh_kernel<<<(V * C / 4 + 255) / 256, 256, 0, stream>>>(h, bnsum, bnsq, bn_gamma, bn_beta);
}

// Round 20
// 263.608 us; speedup vs baseline: 2.5090x; 1.0619x over previous
//
#include <hip/hip_runtime.h>

namespace {
constexpr int V = 50000;
constexpr int E = 640000;
constexpr int HALF = 320000;
constexpr int NREL2 = 474;
constexpr int C = 128;
constexpr int NCHUNK = (V + 255) / 256; // 196
constexpr int NQBLK = V / 16;           // 3125 node-blocks in qnode
constexpr int RELBLK = (NREL2 + 1) / 2; // 237 relout blocks folded into qnode
constexpr int HISTBLK = E / 256;        // 2500 hist blocks folded into qnode
constexpr int NTILES = V / 16;          // 3125
}

typedef _Float16 h4 __attribute__((ext_vector_type(4)));
typedef _Float16 f16x8 __attribute__((ext_vector_type(8)));
typedef float f32x4 __attribute__((ext_vector_type(4)));

// ---- precompute: c[k,i], b[k,i], Mh + LWh (f16 frag layouts), rel_h cast ---
// Mh[u], u = (((d*4+k)*2+ot)*16+o16)*128 + i  (d: 0=in 1=out, o = ot*16+o16)
// LWh[u], u = (ot*16+o16)*128 + i ; value = lr[i]*lw[i][o]/3
__global__ void prep_kernel(const float* __restrict__ nrw, const float* __restrict__ nw,
                            const float* __restrict__ inw, const float* __restrict__ outw,
                            const float* __restrict__ aw, const float* __restrict__ rel,
                            const float* __restrict__ lr, const float* __restrict__ lw,
                            float* __restrict__ cbuf, float* __restrict__ bbuf,
                            _Float16* __restrict__ Mh, _Float16* __restrict__ rel_h,
                            _Float16* __restrict__ LWh) {
  int tid = blockIdx.x * 256 + threadIdx.x;
  if (tid < 512) {
    int k = tid >> 7, i = tid & 127;
    float acc = 0.f;
    for (int d = 0; d < 32; ++d) acc += nrw[k*4096 + i*32 + d] * aw[d];
    cbuf[tid] = acc;
  } else if (tid < 1024) {
    int u = tid - 512; int k = u >> 7, i = u & 127;
    float acc = 0.f;
    for (int d = 0; d < 32; ++d) acc += nw[k*4096 + i*32 + d] * aw[32 + d];
    bbuf[u] = acc;
  } else if (tid < 1024 + 16384) {
    int u = tid - 1024; int k = u >> 12, rem = u & 4095, i = rem >> 5, o = rem & 31;
    float acc = 0.f;
    for (int d = 0; d < 32; ++d) acc += nrw[k*4096 + i*32 + d] * inw[k*1024 + d*32 + o];
    Mh[(((k) * 2 + (o >> 4)) * 16 + (o & 15)) * 128 + i] = (_Float16)acc;
  } else if (tid < 1024 + 32768) {
    int u = tid - 1024 - 16384; int k = u >> 12, rem = u & 4095, i = rem >> 5, o = rem & 31;
    float acc = 0.f;
    for (int d = 0; d < 32; ++d) acc += nrw[k*4096 + i*32 + d] * outw[k*1024 + d*32 + o];
    Mh[(((4 + k) * 2 + (o >> 4)) * 16 + (o & 15)) * 128 + i] = (_Float16)acc;
  } else if (tid < 1024 + 32768 + NREL2 * C / 8) {
    int u = tid - 1024 - 32768;  // 8-elem chunk of rel table
    const float4 v0 = *(const float4*)(rel + (size_t)u * 8);
    const float4 v1 = *(const float4*)(rel + (size_t)u * 8 + 4);
    f16x8 o;
    o[0] = (_Float16)v0.x; o[1] = (_Float16)v0.y;
    o[2] = (_Float16)v0.z; o[3] = (_Float16)v0.w;
    o[4] = (_Float16)v1.x; o[5] = (_Float16)v1.y;
    o[6] = (_Float16)v1.z; o[7] = (_Float16)v1.w;
    *(f16x8*)(rel_h + (size_t)u * 8) = o;
  } else if (tid < 1024 + 32768 + NREL2 * C / 8 + 16384) {
    int u = tid - 1024 - 32768 - NREL2 * C / 8;  // [o(128)][i(128)]
    int o = u >> 7, i = u & 127;
    float v = lr[i] * lw[i * C + o] * (1.f / 3.f);
    LWh[u] = (_Float16)v;
  }
}

// ---- q[t,k] = node_repr[t].b_k (16 lanes/node) + f16 node cast.
// Blocks [NQBLK, NQBLK+RELBLK): rel_out = rel @ w_rel (2 rows/block).
// Blocks [NQBLK+RELBLK, ...): edge histogram (cnt/cin atomics). -------------
__global__ __launch_bounds__(256) void qnode_kernel(const float* __restrict__ nrp,
                                                    const float* __restrict__ bbuf,
                                                    float* __restrict__ qbuf,
                                                    _Float16* __restrict__ nrp_h,
                                                    const float* __restrict__ rel,
                                                    const float* __restrict__ wrel,
                                                    float* __restrict__ rel_out,
                                                    const int* __restrict__ dst,
                                                    int* __restrict__ cnt,
                                                    int* __restrict__ cin) {
  if (blockIdx.x >= NQBLK + RELBLK) {  // folded histogram
    int e = (blockIdx.x - NQBLK - RELBLK) * 256 + threadIdx.x;
    if (e < E) {
      int t = dst[e];
      atomicAdd(&cnt[t], 1);
      if (e < HALF) atomicAdd(&cin[t], 1);
    }
    return;
  }
  if (blockIdx.x >= NQBLK) {  // folded relout (block-uniform branch)
    __shared__ float rr2[2][128];
    const int bb = blockIdx.x - NQBLK;
    const int half = threadIdx.x >> 7;
    const int t128 = threadIdx.x & 127;
    const int row = bb * 2 + half;
    if (row < NREL2) rr2[half][t128] = rel[row * C + t128];
    __syncthreads();
    if (row < NREL2) {
      float acc = 0.f;
#pragma unroll 4
      for (int i = 0; i < C; ++i) acc += rr2[half][i] * wrel[i * C + t128];
      rel_out[row * C + t128] = acc;
    }
    return;
  }
  const int t = blockIdx.x * 16 + (threadIdx.x >> 4);
  const int l = threadIdx.x & 15;
  if (t >= V) return;
  const float* row = nrp + (size_t)t * C + l * 8;
  float4 a0 = *(const float4*)(row);
  float4 a1 = *(const float4*)(row + 4);
  {
    f16x8 o;
    o[0] = (_Float16)a0.x; o[1] = (_Float16)a0.y;
    o[2] = (_Float16)a0.z; o[3] = (_Float16)a0.w;
    o[4] = (_Float16)a1.x; o[5] = (_Float16)a1.y;
    o[6] = (_Float16)a1.z; o[7] = (_Float16)a1.w;
    *(f16x8*)(nrp_h + (size_t)t * C + l * 8) = o;
  }
  float p[4];
#pragma unroll
  for (int k = 0; k < 4; ++k) {
    const float* brow = bbuf + k * C + l * 8;
    float4 b0 = *(const float4*)(brow);
    float4 b1 = *(const float4*)(brow + 4);
    p[k] = a0.x * b0.x + a0.y * b0.y + a0.z * b0.z + a0.w * b0.w
         + a1.x * b1.x + a1.y * b1.y + a1.z * b1.z + a1.w * b1.w;
  }
#pragma unroll
  for (int m = 1; m < 16; m <<= 1) {
#pragma unroll
    for (int k = 0; k < 4; ++k) p[k] += __shfl_xor(p[k], m);
  }
  if (l == 0) *(float4*)(qbuf + 4 * (size_t)t) = make_float4(p[0], p[1], p[2], p[3]);
}

// ---------------- CSR scan ---------------------------------------------------
__global__ void scan_sum_kernel(const int* __restrict__ cnt, int* __restrict__ bsum) {
  __shared__ int sd[256];
  int tid = threadIdx.x;
  int idx = blockIdx.x * 256 + tid;
  int v = (idx < V) ? cnt[idx] : 0;
  sd[tid] = v; __syncthreads();
  for (int s = 128; s > 0; s >>= 1) {
    if (tid < s) sd[tid] += sd[tid + s];
    __syncthreads();
  }
  if (tid == 0) bsum[blockIdx.x] = sd[0];
}

// per-block scan + redundant top-scan of the 196 block sums (folds scan_top);
// writes ninfo[t] = {off, deg, nin, 0}
__global__ void scan_apply_kernel(const int* __restrict__ cnt, const int* __restrict__ cin,
                                  const int* __restrict__ bsum, int4* __restrict__ ninfo) {
  __shared__ int sd[256];
  __shared__ int sb[256];
  int tid = threadIdx.x;
  int idx = blockIdx.x * 256 + tid;
  // top-scan (inclusive) of block sums — redundant per block, cheap
  int b = (tid < NCHUNK) ? bsum[tid] : 0;
  sb[tid] = b; __syncthreads();
  for (int ofs = 1; ofs < 256; ofs <<= 1) {
    int t2 = (tid >= ofs) ? sb[tid - ofs] : 0;
    __syncthreads();
    sb[tid] += t2;
    __syncthreads();
  }
  const int blockoff = (blockIdx.x == 0) ? 0 : sb[blockIdx.x - 1];
  // per-node scan
  int v = (idx < V) ? cnt[idx] : 0;
  sd[tid] = v; __syncthreads();
  for (int ofs = 1; ofs < 256; ofs <<= 1) {
    int t2 = (tid >= ofs) ? sd[tid - ofs] : 0;
    __syncthreads();
    sd[tid] += t2;
    __syncthreads();
  }
  if (idx < V) {
    ninfo[idx] = make_int4(blockoff + sd[tid] - v, v, cin[idx], 0);
  }
}

// place edges: in-edges (e < HALF) packed at off[t], out-edges after cin[t];
// em = {src|etype<<16, norm bits} single 8B store per edge.
__global__ void place_kernel(const int* __restrict__ dst, const int* __restrict__ src,
                             const int* __restrict__ etype, const float* __restrict__ norm,
                             const int4* __restrict__ ninfo,
                             int* __restrict__ cur_in, int* __restrict__ cur_out,
                             int2* __restrict__ em) {
  int e = blockIdx.x * 256 + threadIdx.x;
  if (e < E) {
    int t = dst[e];
    int4 nf = ninfo[t];
    int pos;
    if (e < HALF) {
      pos = nf.x + atomicAdd(&cur_in[t], 1);
    } else {
      pos = nf.x + nf.z + atomicAdd(&cur_out[t], 1);
    }
    em[pos] = make_int2(src[e] | (etype[e] << 16), __float_as_int(norm[e]));
  }
}

// ---------------- fused: gather + attention + z accum + MFMA ----------------
// Round-9 config (best measured): 256 threads, 4 waves, 16 nodes/block.
__global__ __launch_bounds__(256) void fused_kernel(
    const _Float16* __restrict__ nrp_h, const _Float16* __restrict__ rel_h,
    const int4* __restrict__ ninfo, const float* __restrict__ qbuf,
    const float* __restrict__ cbuf, const int2* __restrict__ em,
    const _Float16* __restrict__ Mh, float* __restrict__ h) {
  __shared__ __align__(16) _Float16 z16[16384];  // 16 nodes x 2048B, swizzled
  const int w = threadIdx.x >> 6;
  const int lane = threadIdx.x & 63;
  const int dirg = lane >> 5;        // 0: in-edges, 1: out-edges
  const int slot = (lane >> 4) & 1;  // edge slot within dir
  const int ll = lane & 15;          // 8-channel chunk
  const int ch0 = ll * 8;

  // c_k chunks: register-resident (8 floats per k)
  float4 ckA[4], ckB[4];
#pragma unroll
  for (int k = 0; k < 4; ++k) {
    ckA[k] = *(const float4*)(cbuf + k * C + ch0);
    ckB[k] = *(const float4*)(cbuf + k * C + ch0 + 4);
  }

  // ---- phase 1: per-node edge loop, 4 edges per wave-iteration ----
  for (int nn = 0; nn < 4; ++nn) {
    const int node = w * 4 + nn;               // 0..15
    const int t = blockIdx.x * 16 + node;
    const int4 nfo = ninfo[t];
    const int start = nfo.x, deg = nfo.y, ni = nfo.z;
    const float4 q4 = *(const float4*)(qbuf + 4 * (size_t)t);
    const int sidx = dirg ? ni : 0;
    const int nmy = dirg ? (deg - ni) : ni;
    const int nmax = max(ni, deg - ni);        // wave-uniform

    float4 zA[4], zB[4];
#pragma unroll
    for (int k = 0; k < 4; ++k) {
      zA[k] = make_float4(0.f, 0.f, 0.f, 0.f);
      zB[k] = make_float4(0.f, 0.f, 0.f, 0.f);
    }

    if (nmax > 0) {
      // stage: em0 -> current (j), em1 -> next (j+2); rows for j in flight
      int2 em0 = em[start + min(sidx + slot, deg - 1)];
      int2 em1 = em[start + min(sidx + 2 + slot, deg - 1)];
      f16x8 ah = *(const f16x8*)(nrp_h + (size_t)(em0.x & 0xFFFF) * C + ch0);
      f16x8 bh = *(const f16x8*)(rel_h + (size_t)((em0.x >> 16) & 0x1FF) * C + ch0);

      for (int j = 0; j < nmax; j += 2) {
        // stage meta for j+4 (no dependencies; wave-uniform condition)
        int2 em2 = em1;
        if (j + 4 < nmax) em2 = em[start + min(sidx + j + 4 + slot, deg - 1)];
        // stage rows for j+2 using em1 (arrived a full iteration ago)
        f16x8 ahn = ah, bhn = bh;
        if (j + 2 < nmax) {
          ahn = *(const f16x8*)(nrp_h + (size_t)(em1.x & 0xFFFF) * C + ch0);
          bhn = *(const f16x8*)(rel_h + (size_t)((em1.x >> 16) & 0x1FF) * C + ch0);
        }
        // compute current edge (j + slot): x = a*b in f32
        float4 xA, xB;
        xA.x = (float)ah[0] * (float)bh[0];
        xA.y = (float)ah[1] * (float)bh[1];
        xA.z = (float)ah[2] * (float)bh[2];
        xA.w = (float)ah[3] * (float)bh[3];
        xB.x = (float)ah[4] * (float)bh[4];
        xB.y = (float)ah[5] * (float)bh[5];
        xB.z = (float)ah[6] * (float)bh[6];
        xB.w = (float)ah[7] * (float)bh[7];
        float p0 = xA.x * ckA[0].x + xA.y * ckA[0].y + xA.z * ckA[0].z + xA.w * ckA[0].w
                 + xB.x * ckB[0].x + xB.y * ckB[0].y + xB.z * ckB[0].z + xB.w * ckB[0].w;
        float p1 = xA.x * ckA[1].x + xA.y * ckA[1].y + xA.z * ckA[1].z + xA.w * ckA[1].w
                 + xB.x * ckB[1].x + xB.y * ckB[1].y + xB.z * ckB[1].z + xB.w * ckB[1].w;
        float p2 = xA.x * ckA[2].x + xA.y * ckA[2].y + xA.z * ckA[2].z + xA.w * ckA[2].w
                 + xB.x * ckB[2].x + xB.y * ckB[2].y + xB.z * ckB[2].z + xB.w * ckB[2].w;
        float p3 = xA.x * ckA[3].x + xA.y * ckA[3].y + xA.z * ckA[3].z + xA.w * ckA[3].w
                 + xB.x * ckB[3].x + xB.y * ckB[3].y + xB.z * ckB[3].z + xB.w * ckB[3].w;
#pragma unroll
        for (int m = 1; m < 16; m <<= 1) {
          p0 += __shfl_xor(p0, m);
          p1 += __shfl_xor(p1, m);
          p2 += __shfl_xor(p2, m);
          p3 += __shfl_xor(p3, m);
        }
        // softmax (no max-sub: logits are relu'd and small for this model)
        float l0 = fmaxf(p0 + q4.x, 0.f);
        float l1 = fmaxf(p1 + q4.y, 0.f);
        float l2 = fmaxf(p2 + q4.z, 0.f);
        float l3 = fmaxf(p3 + q4.w, 0.f);
        float e0f = __expf(l0), e1f = __expf(l1);
        float e2f = __expf(l2), e3f = __expf(l3);
        float nr = __int_as_float(em0.y);
        float inv = ((j + slot) < nmy) ? (nr / (e0f + e1f + e2f + e3f)) : 0.f;
        float w0 = e0f * inv, w1 = e1f * inv, w2 = e2f * inv, w3 = e3f * inv;
        zA[0].x += w0 * xA.x; zA[0].y += w0 * xA.y; zA[0].z += w0 * xA.z; zA[0].w += w0 * xA.w;
        zB[0].x += w0 * xB.x; zB[0].y += w0 * xB.y; zB[0].z += w0 * xB.z; zB[0].w += w0 * xB.w;
        zA[1].x += w1 * xA.x; zA[1].y += w1 * xA.y; zA[1].z += w1 * xA.z; zA[1].w += w1 * xA.w;
        zB[1].x += w1 * xB.x; zB[1].y += w1 * xB.y; zB[1].z += w1 * xB.z; zB[1].w += w1 * xB.w;
        zA[2].x += w2 * xA.x; zA[2].y += w2 * xA.y; zA[2].z += w2 * xA.z; zA[2].w += w2 * xA.w;
        zB[2].x += w2 * xB.x; zB[2].y += w2 * xB.y; zB[2].z += w2 * xB.z; zB[2].w += w2 * xB.w;
        zA[3].x += w3 * xA.x; zA[3].y += w3 * xA.y; zA[3].z += w3 * xA.z; zA[3].w += w3 * xA.w;
        zB[3].x += w3 * xB.x; zB[3].y += w3 * xB.y; zB[3].z += w3 * xB.z; zB[3].w += w3 * xB.w;
        // rotate pipeline
        em0 = em1; em1 = em2;
        ah = ahn; bh = bhn;
      }
    }

    // combine the two slots of each dir (lane ^ 16 stays within the dir half)
#pragma unroll
    for (int k = 0; k < 4; ++k) {
      zA[k].x += __shfl_xor(zA[k].x, 16);
      zA[k].y += __shfl_xor(zA[k].y, 16);
      zA[k].z += __shfl_xor(zA[k].z, 16);
      zA[k].w += __shfl_xor(zA[k].w, 16);
      zB[k].x += __shfl_xor(zB[k].x, 16);
      zB[k].y += __shfl_xor(zB[k].y, 16);
      zB[k].z += __shfl_xor(zB[k].z, 16);
      zB[k].w += __shfl_xor(zB[k].w, 16);
    }
    // write f16 z: byte = node*2048 + dir*1024 + k*256 + ((ll*16) ^ swz)
    if (slot == 0) {
      const int swz = (node & 7) << 4;
      char* zb = (char*)z16 + node * 2048 + dirg * 1024 + ((ll * 16) ^ swz);
#pragma unroll
      for (int k = 0; k < 4; ++k) {
        f16x8 o;
        o[0] = (_Float16)zA[k].x; o[1] = (_Float16)zA[k].y;
        o[2] = (_Float16)zA[k].z; o[3] = (_Float16)zA[k].w;
        o[4] = (_Float16)zB[k].x; o[5] = (_Float16)zB[k].y;
        o[6] = (_Float16)zB[k].z; o[7] = (_Float16)zB[k].w;
        *(f16x8*)(zb + k * 256) = o;
      }
    }
  }
  __syncthreads();

  // ---- phase 2: MFMA contraction; wave = k ----
  const int kk = w;
  const int lo16 = lane & 15;       // A row (node) / B col (o) / C col (o)
  const int kq = lane >> 4;         // k-chunk quarter
  {
    const int anode = lo16;
    const int aswz = (anode & 7) << 4;
    const char* zb = (const char*)z16 + anode * 2048 + kk * 256;
    f16x8 a[2][4];
#pragma unroll
    for (int d = 0; d < 2; ++d)
#pragma unroll
      for (int kc = 0; kc < 4; ++kc)
        a[d][kc] = *(const f16x8*)(zb + d * 1024 + ((kc * 64 + kq * 16) ^ aswz));

    f32x4 c0 = {0.f, 0.f, 0.f, 0.f};
    f32x4 c1 = {0.f, 0.f, 0.f, 0.f};
#pragma unroll
    for (int d = 0; d < 2; ++d)
#pragma unroll
      for (int kc = 0; kc < 4; ++kc) {
        const _Float16* mb = Mh + (((d * 4 + kk) * 2) * 16 + lo16) * 128 + kc * 32 + kq * 8;
        f16x8 b0 = *(const f16x8*)(mb);
        f16x8 b1 = *(const f16x8*)(mb + 2048);
        c0 = __builtin_amdgcn_mfma_f32_16x16x32_f16(a[d][kc], b0, c0, 0, 0, 0);
        c1 = __builtin_amdgcn_mfma_f32_16x16x32_f16(a[d][kc], b1, c1, 0, 0, 0);
      }

    const float third = 1.f / 3.f;
#pragma unroll
    for (int r = 0; r < 4; ++r) {
      int tt = blockIdx.x * 16 + kq * 4 + r;
      if (tt < V) {
        size_t hb = (size_t)tt * C + kk * 32 + lo16;
        h[hb] = c0[r] * third;
        h[hb + 16] = c1[r] * third;
      }
    }
  }
}

// ---------------- self-loop (MFMA) + bias + BN partial stats ----------------
// Persistent: 640 blocks x 256 threads grid-stride over 16-row h tiles
// (5 tiles/block amortization — measured best at 640).
__global__ __launch_bounds__(256) void selfloop_kernel(
    float* __restrict__ h, const _Float16* __restrict__ LWh,
    const float* __restrict__ bias,
    float* __restrict__ bnsum, float* __restrict__ bnsq) {
  __shared__ __align__(16) _Float16 hf[2048];  // 16 rows x 256B, swizzled
  const int tid = threadIdx.x;
  const int w = tid >> 6, lane = tid & 63;
  const int row = tid >> 4;          // loader row 0..15
  const int l = tid & 15;            // loader 8-chunk
  const int lo16 = lane & 15;
  const int kq = lane >> 4;
  const float bv0 = bias[w * 32 + lo16];
  const float bv1 = bias[w * 32 + 16 + lo16];
  float s0 = 0.f, s1 = 0.f, sq0 = 0.f, sq1 = 0.f;

  const int aswz = (lo16 & 7) << 4;
  const int lswz = (row & 7) << 4;

  for (int tile = blockIdx.x; tile < NTILES; tile += gridDim.x) {
    // stage h tile as f16 (swizzled)
    {
      const float* hp = h + (size_t)(tile * 16 + row) * C + l * 8;
      float4 v0 = *(const float4*)(hp);
      float4 v1 = *(const float4*)(hp + 4);
      f16x8 o;
      o[0] = (_Float16)v0.x; o[1] = (_Float16)v0.y;
      o[2] = (_Float16)v0.z; o[3] = (_Float16)v0.w;
      o[4] = (_Float16)v1.x; o[5] = (_Float16)v1.y;
      o[6] = (_Float16)v1.z; o[7] = (_Float16)v1.w;
      *(f16x8*)((char*)hf + row * 256 + ((l * 16) ^ lswz)) = o;
    }
    __syncthreads();

    // MFMA: wave w -> output otiles 2w, 2w+1
    const char* zb = (const char*)hf + lo16 * 256;
    f32x4 c0 = {0.f, 0.f, 0.f, 0.f};
    f32x4 c1 = {0.f, 0.f, 0.f, 0.f};
#pragma unroll
    for (int kc = 0; kc < 4; ++kc) {
      f16x8 a = *(const f16x8*)(zb + ((kc * 64 + kq * 16) ^ aswz));
      const _Float16* mb = LWh + ((w * 2) * 16 + lo16) * 128 + kc * 32 + kq * 8;
      f16x8 b0 = *(const f16x8*)(mb);
      f16x8 b1 = *(const f16x8*)(mb + 2048);
      c0 = __builtin_amdgcn_mfma_f32_16x16x32_f16(a, b0, c0, 0, 0, 0);
      c1 = __builtin_amdgcn_mfma_f32_16x16x32_f16(a, b1, c1, 0, 0, 0);
    }

    // epilogue: h_new = h_orig(f32) + c + bias; BN stats
#pragma unroll
    for (int r = 0; r < 4; ++r) {
      int tt = tile * 16 + kq * 4 + r;
      size_t hb = (size_t)tt * C + w * 32 + lo16;
      float h0 = h[hb] + c0[r] + bv0;
      float h1 = h[hb + 16] + c1[r] + bv1;
      h[hb] = h0;
      h[hb + 16] = h1;
      s0 += h0; s1 += h1; sq0 += h0 * h0; sq1 += h1 * h1;
    }
    __syncthreads();  // done reading hf before next tile's writes
  }

  // reduce over kq (lanes lo16, +16, +32, +48), one atomic batch per column
  s0 += __shfl_xor(s0, 16); s0 += __shfl_xor(s0, 32);
  s1 += __shfl_xor(s1, 16); s1 += __shfl_xor(s1, 32);
  sq0 += __shfl_xor(sq0, 16); sq0 += __shfl_xor(sq0, 32);
  sq1 += __shfl_xor(sq1, 16); sq1 += __shfl_xor(sq1, 32);
  if (kq == 0) {
    atomicAdd(&bnsum[w * 32 + lo16], s0);
    atomicAdd(&bnsum[w * 32 + 16 + lo16], s1);
    atomicAdd(&bnsq[w * 32 + lo16], sq0);
    atomicAdd(&bnsq[w * 32 + 16 + lo16], sq1);
  }
}

// ---------------- BN finalize + tanh (fused) --------------------------------
__global__ void tanh_kernel(float* __restrict__ h,
                            const float* __restrict__ bnsum, const float* __restrict__ bnsq,
                            const float* __restrict__ gamma, const float* __restrict__ beta) {
  int idx = blockIdx.x * 256 + threadIdx.x;
  int base = idx * 4;
  if (base >= V * C) return;
  int j = base & 127;
  const float invV = 1.f / (float)V;
  float4 v = *(float4*)(h + base);
  float o[4] = {v.x, v.y, v.z, v.w};
#pragma unroll
  for (int cidx = 0; cidx < 4; ++cidx) {
    float mean = bnsum[j + cidx] * invV;
    float var = bnsq[j + cidx] * invV - mean * mean;
    float sc = gamma[j + cidx] * rsqrtf(var + 1e-5f);
    float sh = beta[j + cidx] - sc * mean;
    o[cidx] = tanhf(sc * o[cidx] + sh);
  }
  v.x = o[0]; v.y = o[1]; v.z = o[2]; v.w = o[3];
  *(float4*)(h + base) = v;
}

extern "C" void kernel_launch(void* const* d_in, const int* in_sizes, int n_in,
                              void* d_out, int out_size, void* d_ws, size_t ws_size,
                              hipStream_t stream) {
  const float* node_repr  = (const float*)d_in[0];
  const float* rel_repr   = (const float*)d_in[1];
  const int*   src        = (const int*)d_in[2];
  const int*   dst        = (const int*)d_in[3];
  const int*   etype      = (const int*)d_in[4];
  const float* norm       = (const float*)d_in[5];
  const float* node_w     = (const float*)d_in[6];
  const float* node_rel_w = (const float*)d_in[7];
  const float* in_w       = (const float*)d_in[8];
  const float* out_w      = (const float*)d_in[9];
  const float* att_w      = (const float*)d_in[10];
  const float* loop_rel   = (const float*)d_in[11];
  const float* loop_w     = (const float*)d_in[12];
  const float* w_rel      = (const float*)d_in[13];
  const float* bias       = (const float*)d_in[14];
  const float* bn_gamma   = (const float*)d_in[15];
  const float* bn_beta    = (const float*)d_in[16];

  float* out = (float*)d_out;
  float* h = out;                       // [V,128] accumulator, finalized in place
  float* rel_out = out + (size_t)V * C; // [474,128]

  // workspace layout (16B alignment maintained for int4/float4 users)
  int* cnt = (int*)d_ws;                // V
  int* cur_in = cnt + V;                // V
  int* cin = cur_in + V;                // V
  int* cur_out = cin + V;               // V
  float* bnsum = (float*)(cur_out + V); // 128
  float* bnsq = bnsum + 128;            // 128  -- zero region ends (4V+256)
  int* bsum = (int*)(bnsq + 128);       // 256
  int4* ninfo = (int4*)(bsum + 256);    // V int4 (16B aligned: 4V+512 ints)
  int2* em = (int2*)(ninfo + V);        // E int2
  float* qbuf = (float*)(em + E);       // 4V
  float* cbuf = qbuf + 4 * V;           // 512
  float* bbuf = cbuf + 512;             // 512
  _Float16* Mh = (_Float16*)(bbuf + 512);   // 32768 halves (f16 B-frag layout)
  _Float16* LWh = Mh + 32768;           // 16384 halves (selfloop B-frag)
  _Float16* nrp_h = LWh + 16384;        // V*C halves (12.8 MB)
  _Float16* rel_h = nrp_h + (size_t)V * C; // 474*128 halves

  hipMemsetAsync(cnt, 0, (size_t)(4 * V + 256) * 4, stream);

  prep_kernel<<<(1024 + 32768 + NREL2 * C / 8 + 16384 + 255) / 256, 256, 0, stream>>>(
      node_rel_w, node_w, in_w, out_w, att_w, rel_repr, loop_rel, loop_w,
      cbuf, bbuf, Mh, rel_h, LWh);
  qnode_kernel<<<NQBLK + RELBLK + HISTBLK, 256, 0, stream>>>(
      node_repr, bbuf, qbuf, nrp_h, rel_repr, w_rel, rel_out, dst, cnt, cin);
  scan_sum_kernel<<<NCHUNK, 256, 0, stream>>>(cnt, bsum);
  scan_apply_kernel<<<NCHUNK, 256, 0, stream>>>(cnt, cin, bsum, ninfo);
  place_kernel<<<E / 256, 256, 0, stream>>>(dst, src, etype, norm, ninfo,
                                            cur_in, cur_out, em);
  fused_kernel<<<(V + 15) / 16, 256, 0, stream>>>(nrp_h, rel_h, ninfo,
                                                  qbuf, cbuf, em, Mh, h);
  selfloop_kernel<<<640, 256, 0, stream>>>(h, LWh, bias, bnsum, bnsq);
  tanh_kernel<<<(V * C / 4 + 255) / 256, 256, 0, stream>>>(h, bnsum, bnsq, bn_gamma, bn_beta);
}